// Round 2
// baseline (5304.732 us; speedup 1.0000x reference)
//
#include <hip/hip_runtime.h>
#include <stdint.h>

// ---------------------------------------------------------------------------
// EMMPTNet: 2-layer bidir LSTM (T=2048,H=128) -> self-attn (attn matrix is
// output 1) -> 2-hop GCN (50k nodes, 600k edges) -> MLP (output 0).
// All float tensors are fp32 (verified: threshold 2.8125e-3 = 2% absmax with
// no bf16 floor => _any_bf16 False). Integers are int32.
// ---------------------------------------------------------------------------

#define T_SEQ 2048
#define NNODE 50000
#define NEDGE 600000

static __device__ __forceinline__ float sigf(float x) { return 1.f / (1.f + __expf(-x)); }
static __device__ __forceinline__ float tanh_fast(float x) { return 1.f - 2.f / (1.f + __expf(2.f * x)); }

// ---------------- workspace layout (fp32 elements) ----------------
constexpr size_t OFF_XG    = 0;                                  // [2][2048][512]
constexpr size_t OFF_H0    = OFF_XG + (size_t)2 * 2048 * 512;    // [2048][256]
constexpr size_t OFF_H1    = OFF_H0 + (size_t)2048 * 256;        // [2048][256]
constexpr size_t OFF_Q     = OFF_H1 + (size_t)2048 * 256;        // [2048][128]
constexpr size_t OFF_K     = OFF_Q + (size_t)2048 * 128;
constexpr size_t OFF_V     = OFF_K + (size_t)2048 * 128;
constexpr size_t OFF_AROW  = OFF_V + (size_t)2048 * 128;         // softmax row 2047
constexpr size_t OFF_AV    = OFF_AROW + 2048;                    // [128]
constexpr size_t OFF_FEATS = OFF_AV + 128;                       // [1152]
constexpr size_t OFF_GSUM  = OFF_FEATS + 1152;                   // [128]
constexpr size_t OFF_AGG1  = OFF_GSUM + 128;                     // [50000][128]
constexpr size_t WS_FLOATS = OFF_AGG1 + (size_t)NNODE * 128;     // ~10.3M floats

// ---------------- layer-0 input projection: xg = g_mol @ w_ih.T + b_ih + b_hh
__global__ __launch_bounds__(512) void xg0_kernel(
    const float* __restrict__ g_mol, const float* __restrict__ w_ih,
    const float* __restrict__ b_ih, const float* __restrict__ b_hh,
    float* __restrict__ xg)
{
    int r = threadIdx.x;
    int t = blockIdx.x & 2047;
    int d = blockIdx.x >> 11;
    __shared__ float xrow[17];
    if (r < 17) xrow[r] = g_mol[t * 17 + r];
    __syncthreads();
    const float* w = w_ih + ((size_t)d * 512 + r) * 17;
    float acc = b_ih[d * 512 + r] + b_hh[d * 512 + r];
#pragma unroll
    for (int k = 0; k < 17; ++k) acc += xrow[k] * w[k];
    xg[((size_t)d * T_SEQ + t) * 512 + r] = acc;
}

// ---------------- layer-1 input projection: xg = h0 @ w_ih1.T + b_ih + b_hh
__global__ __launch_bounds__(512) void xg1_kernel(
    const float* __restrict__ h0, const float* __restrict__ w_ih,
    const float* __restrict__ b_ih, const float* __restrict__ b_hh,
    float* __restrict__ xg)
{
    int r = threadIdx.x;
    int t = blockIdx.x & 2047;
    int d = blockIdx.x >> 11;
    __shared__ float xrow[256];
    if (r < 256) xrow[r] = h0[(size_t)t * 256 + r];
    __syncthreads();
    const float4* w4 = reinterpret_cast<const float4*>(w_ih + ((size_t)d * 512 + r) * 256);
    const float4* x4 = reinterpret_cast<const float4*>(xrow);
    float acc = b_ih[d * 512 + r] + b_hh[d * 512 + r];
#pragma unroll 8
    for (int k = 0; k < 64; ++k) {
        float4 w = w4[k], x = x4[k];
        acc += x.x * w.x + x.y * w.y + x.z * w.z + x.w * w.w;
    }
    xg[((size_t)d * T_SEQ + t) * 512 + r] = acc;
}

// ---------------- LSTM recurrence: one block per direction, fp32.
// 512 threads: chunk g = tid>>7 in [0,4) covers k in [32g,32g+32); lane
// l = tid&127 owns gate rows {l,128+l,256+l,384+l}. Weights in VGPRs
// (wr[4][32] = 128 VGPRs; __launch_bounds__(512,2) -> 256-VGPR cap, no spill).
// 3-phase step: matvec -> parallel reduce+activate (all 8 waves) -> c/h.
__global__ __launch_bounds__(512, 2) void lstm_rec_kernel(
    const float* __restrict__ xg,   // [2][T][512], biases folded in
    const float* __restrict__ w_hh, // [2][512][128]
    float* __restrict__ hout)       // [T][256]: dir 0 -> cols 0..127, dir 1 -> 128..255
{
    const int dir = blockIdx.x;
    const int tid = threadIdx.x;
    const int g = tid >> 7;
    const int l = tid & 127;

    __shared__ float h_sh[128];
    __shared__ float pbuf[4][512];
    __shared__ float act[512];

    const float* wbase = w_hh + (size_t)dir * 512 * 128;
    float wr[4][32];
#pragma unroll
    for (int m = 0; m < 4; ++m) {
        const float4* wrow = reinterpret_cast<const float4*>(wbase + (size_t)(m * 128 + l) * 128 + 32 * g);
#pragma unroll
        for (int q = 0; q < 8; ++q) {
            float4 w = wrow[q];
            wr[m][4 * q + 0] = w.x; wr[m][4 * q + 1] = w.y;
            wr[m][4 * q + 2] = w.z; wr[m][4 * q + 3] = w.w;
        }
    }

    if (tid < 128) h_sh[tid] = 0.f;
    float c = 0.f;
    __syncthreads();

    const float* xgd = xg + (size_t)dir * T_SEQ * 512;

    for (int s = 0; s < T_SEQ; ++s) {
        const int tt = dir ? (T_SEQ - 1 - s) : s;

        // prefetch this step's xg row (consumed in phase 2, hidden under FMAs)
        float xv = xgd[(size_t)tt * 512 + tid];

        // phase 1: matvec partials over k-chunk g
        const float4* h4 = reinterpret_cast<const float4*>(h_sh + 32 * g);
        float a0 = 0.f, a1 = 0.f, a2 = 0.f, a3 = 0.f;
#pragma unroll
        for (int q = 0; q < 8; ++q) {
            float4 hv = h4[q];   // same address across wave -> LDS broadcast
            a0 += hv.x * wr[0][4 * q] + hv.y * wr[0][4 * q + 1] + hv.z * wr[0][4 * q + 2] + hv.w * wr[0][4 * q + 3];
            a1 += hv.x * wr[1][4 * q] + hv.y * wr[1][4 * q + 1] + hv.z * wr[1][4 * q + 2] + hv.w * wr[1][4 * q + 3];
            a2 += hv.x * wr[2][4 * q] + hv.y * wr[2][4 * q + 1] + hv.z * wr[2][4 * q + 2] + hv.w * wr[2][4 * q + 3];
            a3 += hv.x * wr[3][4 * q] + hv.y * wr[3][4 * q + 1] + hv.z * wr[3][4 * q + 2] + hv.w * wr[3][4 * q + 3];
        }
        pbuf[g][0 * 128 + l] = a0;
        pbuf[g][1 * 128 + l] = a1;
        pbuf[g][2 * 128 + l] = a2;
        pbuf[g][3 * 128 + l] = a3;
        __syncthreads();

        // phase 2: reduce 4 chunks + activation, all 512 threads (row r = tid)
        {
            float p = xv + pbuf[0][tid] + pbuf[1][tid] + pbuf[2][tid] + pbuf[3][tid];
            act[tid] = (tid >= 256 && tid < 384) ? tanh_fast(p) : sigf(p);
        }
        __syncthreads();

        // phase 3: cell/hidden update by lanes 0..127
        if (tid < 128) {
            float iv = act[l], fv = act[128 + l], gv = act[256 + l], ov = act[384 + l];
            c = fv * c + iv * gv;
            float hv = ov * tanh_fast(c);
            h_sh[l] = hv;
            hout[(size_t)tt * 256 + (dir << 7) + l] = hv;
        }
        __syncthreads();
    }
}

// ---------------- q/k/v projection: block per t, 384 threads
__global__ __launch_bounds__(384) void qkv_kernel(
    const float* __restrict__ h1,
    const float* __restrict__ Wq, const float* __restrict__ bq,
    const float* __restrict__ Wk, const float* __restrict__ bk,
    const float* __restrict__ Wv, const float* __restrict__ bv,
    float* __restrict__ q, float* __restrict__ k, float* __restrict__ v)
{
    int t = blockIdx.x, tid = threadIdx.x;
    __shared__ float row[256];
    if (tid < 256) row[tid] = h1[(size_t)t * 256 + tid];
    __syncthreads();
    int which = tid >> 7, j = tid & 127;
    const float* W = (which == 0) ? Wq : (which == 1) ? Wk : Wv;
    const float* B = (which == 0) ? bq : (which == 1) ? bk : bv;
    float* out = (which == 0) ? q : (which == 1) ? k : v;
    const float4* w4 = reinterpret_cast<const float4*>(W + (size_t)j * 256);
    const float4* x4 = reinterpret_cast<const float4*>(row);
    float acc = B[j];
#pragma unroll 8
    for (int kk = 0; kk < 64; ++kk) {
        float4 w = w4[kk], x = x4[kk];
        acc += x.x * w.x + x.y * w.y + x.z * w.z + x.w * w.w;
    }
    out[(size_t)t * 128 + j] = acc;
}

// ---------------- scores = q @ k.T / sqrt(128), written straight into d_out+1
__global__ __launch_bounds__(256) void scores_kernel(
    const float* __restrict__ q, const float* __restrict__ kmat, float* __restrict__ attn)
{
    int bi = blockIdx.y, bj = blockIdx.x, tid = threadIdx.x;
    __shared__ float qs[16][132];
    __shared__ float ks[16][132];
    for (int u = tid; u < 2048; u += 256) {
        int rr = u >> 7, cc = u & 127;
        qs[rr][cc] = q[(size_t)(bi * 16 + rr) * 128 + cc];
        ks[rr][cc] = kmat[(size_t)(bj * 16 + rr) * 128 + cc];
    }
    __syncthreads();
    int ty = tid >> 4, tx = tid & 15;
    const float4* qrow = reinterpret_cast<const float4*>(&qs[ty][0]);
    const float4* krow = reinterpret_cast<const float4*>(&ks[tx][0]);
    float acc = 0.f;
#pragma unroll
    for (int c4 = 0; c4 < 32; ++c4) {
        float4 a = qrow[c4], b = krow[c4];
        acc += a.x * b.x + a.y * b.y + a.z * b.z + a.w * b.w;
    }
    attn[(size_t)(bi * 16 + ty) * 2048 + (bj * 16 + tx)] = acc * 0.08838834764831845f;
}

// ---------------- softmax per row, in place on d_out+1; saves row 2047 fp32
__global__ __launch_bounds__(256) void softmax_kernel(
    float* __restrict__ attn, float* __restrict__ attnrow)
{
    int i = blockIdx.x, tid = threadIdx.x;
    float* row = attn + (size_t)i * 2048;
    __shared__ float red[256];
    float m = -1e30f;
    for (int j = tid; j < 2048; j += 256) m = fmaxf(m, row[j]);
    red[tid] = m; __syncthreads();
    for (int s = 128; s > 0; s >>= 1) { if (tid < s) red[tid] = fmaxf(red[tid], red[tid + s]); __syncthreads(); }
    m = red[0]; __syncthreads();
    float sum = 0.f;
    for (int j = tid; j < 2048; j += 256) sum += __expf(row[j] - m);
    red[tid] = sum; __syncthreads();
    for (int s = 128; s > 0; s >>= 1) { if (tid < s) red[tid] += red[tid + s]; __syncthreads(); }
    float inv = 1.f / red[0];
    for (int j = tid; j < 2048; j += 256) {
        float w = __expf(row[j] - m) * inv;
        row[j] = w;
        if (i == 2047) attnrow[j] = w;
    }
}

// ---------------- av[j] = sum_t attnrow[t] * v[t][j]
__global__ __launch_bounds__(128) void av_kernel(
    const float* __restrict__ attnrow, const float* __restrict__ v, float* __restrict__ av)
{
    int j = threadIdx.x;
    float acc = 0.f;
#pragma unroll 8
    for (int t = 0; t < 2048; ++t) acc += attnrow[t] * v[(size_t)t * 128 + j];
    av[j] = acc;
}

// ---------------- gmol = av @ Wfc.T + bfc -> feats[256..511]
__global__ __launch_bounds__(256) void gmolfc_kernel(
    const float* __restrict__ av, const float* __restrict__ Wfc, const float* __restrict__ bfc,
    float* __restrict__ feats)
{
    int o = threadIdx.x;
    __shared__ float a[128];
    if (o < 128) a[o] = av[o];
    __syncthreads();
    const float4* w4 = reinterpret_cast<const float4*>(Wfc + (size_t)o * 128);
    const float4* a4 = reinterpret_cast<const float4*>(a);
    float acc = bfc[o];
#pragma unroll 8
    for (int kk = 0; kk < 32; ++kk) {
        float4 w = w4[kk], x = a4[kk];
        acc += x.x * w.x + x.y * w.y + x.z * w.z + x.w * w.w;
    }
    feats[256 + o] = acc;
}

// ---------------- GCN hop 1 scatter: agg1[dst] += feat_seq[src] * ew
__global__ __launch_bounds__(256) void scatter1_kernel(
    const float* __restrict__ feat_seq, const float* __restrict__ ew,
    const int* __restrict__ esrc, const int* __restrict__ edst,
    float* __restrict__ agg1)
{
    int idx = blockIdx.x * 256 + threadIdx.x;  // e*32 + jc
    int e = idx >> 5;
    int j0 = (idx & 31) * 4;
    int s = esrc[e], d = edst[e];
    float w = ew[e];
    float4 fv = *reinterpret_cast<const float4*>(feat_seq + (size_t)s * 128 + j0);
    float* dst = agg1 + (size_t)d * 128 + j0;
    atomicAdd(dst + 0, w * fv.x);
    atomicAdd(dst + 1, w * fv.y);
    atomicAdd(dst + 2, w * fv.z);
    atomicAdd(dst + 3, w * fv.w);
}

// ---------------- h1 = relu(agg1 @ W_gc1 + b_gc1), in place
__global__ __launch_bounds__(128) void gc1_kernel(
    float* __restrict__ agg1, const float* __restrict__ W, const float* __restrict__ b)
{
    int n = blockIdx.x, o = threadIdx.x;
    __shared__ float row[128];
    row[o] = agg1[(size_t)n * 128 + o];
    __syncthreads();
    float acc = b[o];
#pragma unroll 4
    for (int k = 0; k < 128; ++k) acc += row[k] * W[(size_t)k * 128 + o];
    agg1[(size_t)n * 128 + o] = fmaxf(acc, 0.f);
}

// ---------------- gsum[j] = sum_e ew[e] * h1[src[e]][j]
__global__ __launch_bounds__(256) void wsum_kernel(
    const float* __restrict__ h1g, const float* __restrict__ ew,
    const int* __restrict__ esrc, float* __restrict__ gsum)
{
    int j = threadIdx.x & 127, half = threadIdx.x >> 7;
    float acc = 0.f;
    for (int e = blockIdx.x * 2 + half; e < NEDGE; e += gridDim.x * 2)
        acc += ew[e] * h1g[(size_t)esrc[e] * 128 + j];
    __shared__ float red[256];
    red[threadIdx.x] = acc;
    __syncthreads();
    if (threadIdx.x < 128) atomicAdd(gsum + j, red[j] + red[j + 128]);
}

// ---------------- feats: hg (=(gsum/N)@W_gc2+b_gc2) + smiles + kmer
__global__ __launch_bounds__(256) void feats_kernel(
    const float* __restrict__ gsum, const float* __restrict__ W_gc2, const float* __restrict__ b_gc2,
    const float* __restrict__ smiles, const float* __restrict__ kmer, float* __restrict__ feats)
{
    int i = blockIdx.x * 256 + threadIdx.x;
    if (i < 256) {
        float dotv = 0.f;
#pragma unroll 4
        for (int k = 0; k < 128; ++k) dotv += gsum[k] * W_gc2[(size_t)k * 256 + i];
        feats[i] = b_gc2[i] + dotv * (1.f / (float)NNODE);
    } else if (i >= 512 && i < 1086) {
        feats[i] = smiles[i - 512];
    } else if (i >= 1086 && i < 1150) {
        feats[i] = kmer[i - 1086];
    }
}

// ---------------- final MLP 1150->575->256->64->1
__global__ __launch_bounds__(1024) void mlp_kernel(
    const float* __restrict__ feats,
    const float* __restrict__ W1, const float* __restrict__ b1,
    const float* __restrict__ W2, const float* __restrict__ b2,
    const float* __restrict__ W3, const float* __restrict__ b3,
    const float* __restrict__ W4, const float* __restrict__ b4,
    float* __restrict__ out)
{
    __shared__ float f0[1152], f1[576], f2[256], f3[64];
    int tid = threadIdx.x;
    for (int u = tid; u < 1150; u += 1024) f0[u] = feats[u];
    __syncthreads();
    if (tid < 575) {
        const float* w = W1 + (size_t)tid * 1150;
        float acc = b1[tid];
        for (int k = 0; k < 1150; ++k) acc += f0[k] * w[k];
        f1[tid] = fmaxf(acc, 0.f);
    }
    __syncthreads();
    if (tid < 256) {
        const float* w = W2 + (size_t)tid * 575;
        float acc = b2[tid];
        for (int k = 0; k < 575; ++k) acc += f1[k] * w[k];
        f2[tid] = fmaxf(acc, 0.f);
    }
    __syncthreads();
    if (tid < 64) {
        const float* w = W3 + (size_t)tid * 256;
        float acc = b3[tid];
        for (int k = 0; k < 256; ++k) acc += f2[k] * w[k];
        f3[tid] = fmaxf(acc, 0.f);
    }
    __syncthreads();
    if (tid == 0) {
        float acc = b4[0];
        for (int k = 0; k < 64; ++k) acc += f3[k] * W4[k];
        out[0] = acc;
    }
}

// ---------------------------------------------------------------------------
extern "C" void kernel_launch(void* const* d_in, const int* in_sizes, int n_in,
                              void* d_out, int out_size, void* d_ws, size_t ws_size,
                              hipStream_t stream)
{
    const float* g_mol   = (const float*)d_in[0];
    const float* feat_seq= (const float*)d_in[1];
    const float* smiles  = (const float*)d_in[2];
    const float* kmer    = (const float*)d_in[3];
    const float* edge_w  = (const float*)d_in[4];
    const float* w_ih0   = (const float*)d_in[5];
    const float* w_hh0   = (const float*)d_in[6];
    const float* b_ih0   = (const float*)d_in[7];
    const float* b_hh0   = (const float*)d_in[8];
    const float* w_ih1   = (const float*)d_in[9];
    const float* w_hh1   = (const float*)d_in[10];
    const float* b_ih1   = (const float*)d_in[11];
    const float* b_hh1   = (const float*)d_in[12];
    const float* Wq      = (const float*)d_in[13];
    const float* bq      = (const float*)d_in[14];
    const float* Wk      = (const float*)d_in[15];
    const float* bk      = (const float*)d_in[16];
    const float* Wv      = (const float*)d_in[17];
    const float* bv      = (const float*)d_in[18];
    const float* Wfc     = (const float*)d_in[19];
    const float* bfc     = (const float*)d_in[20];
    const float* W_gc1   = (const float*)d_in[21];
    const float* b_gc1   = (const float*)d_in[22];
    const float* W_gc2   = (const float*)d_in[23];
    const float* b_gc2   = (const float*)d_in[24];
    const float* W1      = (const float*)d_in[25];
    const float* b1      = (const float*)d_in[26];
    const float* W2      = (const float*)d_in[27];
    const float* b2      = (const float*)d_in[28];
    const float* W3      = (const float*)d_in[29];
    const float* b3      = (const float*)d_in[30];
    const float* W4      = (const float*)d_in[31];
    const float* b4      = (const float*)d_in[32];
    const int* esrc      = (const int*)d_in[33];
    const int* edst      = (const int*)d_in[34];

    float* ws    = (float*)d_ws;
    float* xg    = ws + OFF_XG;
    float* h0    = ws + OFF_H0;
    float* h1    = ws + OFF_H1;
    float* q     = ws + OFF_Q;
    float* k     = ws + OFF_K;
    float* v     = ws + OFF_V;
    float* arow  = ws + OFF_AROW;
    float* av    = ws + OFF_AV;
    float* feats = ws + OFF_FEATS;
    float* gsum  = ws + OFF_GSUM;
    float* agg1  = ws + OFF_AGG1;

    float* out_f = (float*)d_out;
    float* attn  = out_f + 1;   // [2048][2048] fp32, scores then softmax in place

    // zero the GNN accumulators (gsum + agg1 are contiguous)
    hipMemsetAsync(gsum, 0, (size_t)(128 + (size_t)NNODE * 128) * sizeof(float), stream);

    // ---- GNN (independent of LSTM chain) ----
    scatter1_kernel<<<(NEDGE * 32) / 256, 256, 0, stream>>>(feat_seq, edge_w, esrc, edst, agg1);
    gc1_kernel<<<NNODE, 128, 0, stream>>>(agg1, W_gc1, b_gc1);
    wsum_kernel<<<2048, 256, 0, stream>>>(agg1, edge_w, esrc, gsum);
    feats_kernel<<<5, 256, 0, stream>>>(gsum, W_gc2, b_gc2, smiles, kmer, feats);

    // ---- LSTM stack ----
    xg0_kernel<<<4096, 512, 0, stream>>>(g_mol, w_ih0, b_ih0, b_hh0, xg);
    lstm_rec_kernel<<<2, 512, 0, stream>>>(xg, w_hh0, h0);
    xg1_kernel<<<4096, 512, 0, stream>>>(h0, w_ih1, b_ih1, b_hh1, xg);
    lstm_rec_kernel<<<2, 512, 0, stream>>>(xg, w_hh1, h1);

    // ---- attention ----
    qkv_kernel<<<2048, 384, 0, stream>>>(h1, Wq, bq, Wk, bk, Wv, bv, q, k, v);
    scores_kernel<<<dim3(128, 128), 256, 0, stream>>>(q, k, attn);
    softmax_kernel<<<2048, 256, 0, stream>>>(attn, arow);
    av_kernel<<<1, 128, 0, stream>>>(arow, v, av);
    gmolfc_kernel<<<1, 256, 0, stream>>>(av, Wfc, bfc, feats);

    // ---- head ----
    mlp_kernel<<<1, 1024, 0, stream>>>(feats, W1, b1, W2, b2, W3, b3, W4, b4, out_f);
}

// Round 3
// 4126.023 us; speedup vs baseline: 1.2857x; 1.2857x over previous
//
#include <hip/hip_runtime.h>
#include <stdint.h>

// ---------------------------------------------------------------------------
// EMMPTNet: 2-layer bidir LSTM (T=2048,H=128) -> self-attn (attn matrix is
// output 1) -> 2-hop GCN (50k nodes, 600k edges) -> MLP (output 0).
// All float tensors fp32; LSTM recurrent matvec uses packed fp16 + v_dot2
// (fp32 accumulate). c-state, xg, activations stay fp32.
// ---------------------------------------------------------------------------

#define T_SEQ 2048
#define NNODE 50000
#define NEDGE 600000

typedef _Float16 half2_t __attribute__((ext_vector_type(2)));

static __device__ __forceinline__ float sigf(float x) { return 1.f / (1.f + __expf(-x)); }
static __device__ __forceinline__ float tanh_fast(float x) { return 1.f - 2.f / (1.f + __expf(2.f * x)); }

// acc += lo(a)*lo(b) + hi(a)*hi(b) as fp16 pairs, fp32 accumulate
static __device__ __forceinline__ float dot2h(float acc, uint32_t a, uint32_t b) {
#if __has_builtin(__builtin_amdgcn_fdot2)
    return __builtin_amdgcn_fdot2(__builtin_bit_cast(half2_t, a),
                                  __builtin_bit_cast(half2_t, b), acc, false);
#else
    half2_t ha = __builtin_bit_cast(half2_t, a);
    half2_t hb = __builtin_bit_cast(half2_t, b);
    return acc + (float)ha.x * (float)hb.x + (float)ha.y * (float)hb.y;
#endif
}

// ---------------- workspace layout (fp32 elements) ----------------
constexpr size_t OFF_XG    = 0;                                  // [2][2048][512]
constexpr size_t OFF_H0    = OFF_XG + (size_t)2 * 2048 * 512;    // [2048][256]
constexpr size_t OFF_H1    = OFF_H0 + (size_t)2048 * 256;        // [2048][256]
constexpr size_t OFF_Q     = OFF_H1 + (size_t)2048 * 256;        // [2048][128]
constexpr size_t OFF_K     = OFF_Q + (size_t)2048 * 128;
constexpr size_t OFF_V     = OFF_K + (size_t)2048 * 128;
constexpr size_t OFF_AROW  = OFF_V + (size_t)2048 * 128;         // softmax row 2047
constexpr size_t OFF_AV    = OFF_AROW + 2048;                    // [128]
constexpr size_t OFF_FEATS = OFF_AV + 128;                       // [1152]
constexpr size_t OFF_F1    = OFF_FEATS + 1152;                   // [576]
constexpr size_t OFF_F2    = OFF_F1 + 576;                       // [256]
constexpr size_t OFF_GSUM  = OFF_F2 + 256;                       // [128]
constexpr size_t OFF_AGG1  = OFF_GSUM + 128;                     // [50000][128]
constexpr size_t OFF_WPK   = OFF_AGG1 + (size_t)NNODE * 128;     // 2 layers x 65536 u32
constexpr size_t OFF_WT1   = OFF_WPK + 131072;                   // W_gc1 transposed [128][128]
constexpr size_t WS_FLOATS = OFF_WT1 + 16384;

// ---------------- one-time prep: pack w_hh (both layers) to fp16 pairs in the
// per-thread VGPR layout; transpose W_gc1.
// wpk u32 index (per layer): ((dg*128 + l)*4 + m)*16 + kk,  dg = dir*4+g,
// value = half2( w[dir][m*128+l][32g+2kk], w[dir][m*128+l][32g+2kk+1] )
__global__ __launch_bounds__(256) void prep_kernel(
    const float* __restrict__ w_hh0, const float* __restrict__ w_hh1,
    const float* __restrict__ W_gc1,
    uint32_t* __restrict__ wpk, float* __restrict__ Wt)
{
    int i = blockIdx.x * 256 + threadIdx.x;
    if (i < 131072) {
        int layer = i >> 16;
        int r = i & 65535;
        int kk = r & 15, m = (r >> 4) & 3, l = (r >> 6) & 127, dg = r >> 13;
        int dirv = dg >> 2, gg = dg & 3;
        const float* w = layer ? w_hh1 : w_hh0;
        const float* row = w + ((size_t)dirv * 512 + m * 128 + l) * 128;
        int k0 = gg * 32 + kk * 2;
        half2_t hv;
        hv.x = (_Float16)row[k0];
        hv.y = (_Float16)row[k0 + 1];
        wpk[i] = __builtin_bit_cast(uint32_t, hv);
    } else if (i < 131072 + 16384) {
        int j = i - 131072;
        int o = j >> 7, k = j & 127;
        Wt[o * 128 + k] = W_gc1[k * 128 + o];
    }
}

// ---------------- layer-0 input projection: xg = g_mol @ w_ih.T + b_ih + b_hh
__global__ __launch_bounds__(512) void xg0_kernel(
    const float* __restrict__ g_mol, const float* __restrict__ w_ih,
    const float* __restrict__ b_ih, const float* __restrict__ b_hh,
    float* __restrict__ xg)
{
    int r = threadIdx.x;
    int t = blockIdx.x & 2047;
    int d = blockIdx.x >> 11;
    __shared__ float xrow[17];
    if (r < 17) xrow[r] = g_mol[t * 17 + r];
    __syncthreads();
    const float* w = w_ih + ((size_t)d * 512 + r) * 17;
    float acc = b_ih[d * 512 + r] + b_hh[d * 512 + r];
#pragma unroll
    for (int k = 0; k < 17; ++k) acc += xrow[k] * w[k];
    xg[((size_t)d * T_SEQ + t) * 512 + r] = acc;
}

// ---------------- layer-1 input projection, 16 timesteps per block
__global__ __launch_bounds__(512) void xg1_kernel(
    const float* __restrict__ h0, const float* __restrict__ w_ih,
    const float* __restrict__ b_ih, const float* __restrict__ b_hh,
    float* __restrict__ xg)
{
    int b = blockIdx.x;
    int dir = b >> 7, tg = b & 127, t0 = tg * 16;
    int tid = threadIdx.x;
    __shared__ float xs[16 * 256];
    {
        const float4* src = reinterpret_cast<const float4*>(h0 + (size_t)t0 * 256);
        float4* dst = reinterpret_cast<float4*>(xs);
        for (int u = tid; u < 1024; u += 512) dst[u] = src[u];
    }
    __syncthreads();
    int r = tid;
    float bias = b_ih[dir * 512 + r] + b_hh[dir * 512 + r];
    float acc[16];
#pragma unroll
    for (int tt = 0; tt < 16; ++tt) acc[tt] = bias;
    const float4* w4 = reinterpret_cast<const float4*>(w_ih + ((size_t)dir * 512 + r) * 256);
    const float4* xs4 = reinterpret_cast<const float4*>(xs);
    for (int k4 = 0; k4 < 64; ++k4) {
        float4 w = w4[k4];
#pragma unroll
        for (int tt = 0; tt < 16; ++tt) {
            float4 x = xs4[tt * 64 + k4];
            acc[tt] += x.x * w.x + x.y * w.y + x.z * w.z + x.w * w.w;
        }
    }
#pragma unroll
    for (int tt = 0; tt < 16; ++tt)
        xg[((size_t)dir * T_SEQ + t0 + tt) * 512 + r] = acc[tt];
}

// ---------------- fused: blocks 0,1 = LSTM recurrence (one per direction);
// blocks >=2 = GCN hop-1 edge scatter (grid-stride), only when do_scatter.
// LSTM: 512 thr, g=tid>>7 k-chunk of 32, l=tid&127 owns the 4 gate rows of
// h_l. Weights fp16-packed in VGPRs (wr[4][16] u32); h as fp16 in LDS.
__global__ __launch_bounds__(512) __attribute__((amdgpu_waves_per_eu(2, 4)))
void lstm_fused_kernel(
    const float* __restrict__ xg,    // [2][T][512] biases folded
    const uint32_t* __restrict__ wpk,// this layer's packed weights (65536 u32)
    float* __restrict__ hout,        // [T][256]
    const float* __restrict__ feat_seq, const float* __restrict__ ew,
    const int* __restrict__ esrc, const int* __restrict__ edst,
    float* __restrict__ agg1, int do_scatter)
{
    if (blockIdx.x >= 2) {
        if (!do_scatter) return;
        int nb = gridDim.x - 2;
        int total = NEDGE * 32;
        for (int idx = (blockIdx.x - 2) * 512 + threadIdx.x; idx < total; idx += nb * 512) {
            int e = idx >> 5;
            int j0 = (idx & 31) << 2;
            int s = esrc[e], d = edst[e];
            float w = ew[e];
            float4 fv = *reinterpret_cast<const float4*>(feat_seq + (size_t)s * 128 + j0);
            float* dst = agg1 + (size_t)d * 128 + j0;
            atomicAdd(dst + 0, w * fv.x);
            atomicAdd(dst + 1, w * fv.y);
            atomicAdd(dst + 2, w * fv.z);
            atomicAdd(dst + 3, w * fv.w);
        }
        return;
    }

#if __has_builtin(__builtin_amdgcn_s_setprio)
    __builtin_amdgcn_s_setprio(3);   // recurrence is the latency-critical path
#endif
    const int dir = blockIdx.x;
    const int tid = threadIdx.x;
    const int g = tid >> 7;
    const int l = tid & 127;

    __shared__ __align__(16) _Float16 h_half[128];
    __shared__ float pbuf[4][512];
    __shared__ float act[512];

    // load this thread's 64 packed-u32 weights (16 uint4, contiguous)
    const uint4* wt4 = reinterpret_cast<const uint4*>(
        wpk + ((size_t)((dir * 4 + g) * 128 + l)) * 64);
    uint32_t wr[4][16];
#pragma unroll
    for (int m = 0; m < 4; ++m)
#pragma unroll
        for (int j = 0; j < 4; ++j) {
            uint4 wv = wt4[m * 4 + j];
            wr[m][4 * j + 0] = wv.x; wr[m][4 * j + 1] = wv.y;
            wr[m][4 * j + 2] = wv.z; wr[m][4 * j + 3] = wv.w;
        }

    if (tid < 128) h_half[tid] = (_Float16)0.f;
    float c = 0.f;
    __syncthreads();

    const float* xgd = xg + (size_t)dir * T_SEQ * 512;
    const uint4* h4 = reinterpret_cast<const uint4*>(h_half);  // 16 uint4

    for (int s = 0; s < T_SEQ; ++s) {
        const int tt = dir ? (T_SEQ - 1 - s) : s;

        // prefetch xg row element (used in phase 2; latency hidden by matvec)
        float xv = xgd[(size_t)tt * 512 + tid];

        // phase 1: matvec partials over k-chunk g (fp16 dot2, fp32 acc)
        float a0 = 0.f, a1 = 0.f, a2 = 0.f, a3 = 0.f;
#pragma unroll
        for (int q = 0; q < 4; ++q) {
            uint4 hv = h4[g * 4 + q];     // same addr across wave -> broadcast
            a0 = dot2h(a0, hv.x, wr[0][4 * q + 0]);
            a0 = dot2h(a0, hv.y, wr[0][4 * q + 1]);
            a0 = dot2h(a0, hv.z, wr[0][4 * q + 2]);
            a0 = dot2h(a0, hv.w, wr[0][4 * q + 3]);
            a1 = dot2h(a1, hv.x, wr[1][4 * q + 0]);
            a1 = dot2h(a1, hv.y, wr[1][4 * q + 1]);
            a1 = dot2h(a1, hv.z, wr[1][4 * q + 2]);
            a1 = dot2h(a1, hv.w, wr[1][4 * q + 3]);
            a2 = dot2h(a2, hv.x, wr[2][4 * q + 0]);
            a2 = dot2h(a2, hv.y, wr[2][4 * q + 1]);
            a2 = dot2h(a2, hv.z, wr[2][4 * q + 2]);
            a2 = dot2h(a2, hv.w, wr[2][4 * q + 3]);
            a3 = dot2h(a3, hv.x, wr[3][4 * q + 0]);
            a3 = dot2h(a3, hv.y, wr[3][4 * q + 1]);
            a3 = dot2h(a3, hv.z, wr[3][4 * q + 2]);
            a3 = dot2h(a3, hv.w, wr[3][4 * q + 3]);
        }
        pbuf[g][0 * 128 + l] = a0;
        pbuf[g][1 * 128 + l] = a1;
        pbuf[g][2 * 128 + l] = a2;
        pbuf[g][3 * 128 + l] = a3;
        __syncthreads();

        // phase 2: reduce + activation, row r = tid across all 8 waves
        {
            float p = xv + pbuf[0][tid] + pbuf[1][tid] + pbuf[2][tid] + pbuf[3][tid];
            act[tid] = (tid >= 256 && tid < 384) ? tanh_fast(p) : sigf(p);
        }
        __syncthreads();

        // phase 3: cell/hidden update (lanes 0..127)
        if (tid < 128) {
            float iv = act[l], fv = act[128 + l], gv = act[256 + l], ov = act[384 + l];
            c = fv * c + iv * gv;
            float hv = ov * tanh_fast(c);
            h_half[l] = (_Float16)hv;
            hout[(size_t)tt * 256 + (dir << 7) + l] = hv;
        }
        __syncthreads();
    }
}

// ---------------- q/k/v projection: block per t, 384 threads
__global__ __launch_bounds__(384) void qkv_kernel(
    const float* __restrict__ h1,
    const float* __restrict__ Wq, const float* __restrict__ bq,
    const float* __restrict__ Wk, const float* __restrict__ bk,
    const float* __restrict__ Wv, const float* __restrict__ bv,
    float* __restrict__ q, float* __restrict__ k, float* __restrict__ v)
{
    int t = blockIdx.x, tid = threadIdx.x;
    __shared__ float row[256];
    if (tid < 256) row[tid] = h1[(size_t)t * 256 + tid];
    __syncthreads();
    int which = tid >> 7, j = tid & 127;
    const float* W = (which == 0) ? Wq : (which == 1) ? Wk : Wv;
    const float* B = (which == 0) ? bq : (which == 1) ? bk : bv;
    float* out = (which == 0) ? q : (which == 1) ? k : v;
    const float4* w4 = reinterpret_cast<const float4*>(W + (size_t)j * 256);
    const float4* x4 = reinterpret_cast<const float4*>(row);
    float acc = B[j];
#pragma unroll 8
    for (int kk = 0; kk < 64; ++kk) {
        float4 w = w4[kk], x = x4[kk];
        acc += x.x * w.x + x.y * w.y + x.z * w.z + x.w * w.w;
    }
    out[(size_t)t * 128 + j] = acc;
}

// ---------------- scores = q @ k.T / sqrt(128), straight into d_out+1
__global__ __launch_bounds__(256) void scores_kernel(
    const float* __restrict__ q, const float* __restrict__ kmat, float* __restrict__ attn)
{
    int bi = blockIdx.y, bj = blockIdx.x, tid = threadIdx.x;
    __shared__ float qs[16][132];
    __shared__ float ks[16][132];
    for (int u = tid; u < 2048; u += 256) {
        int rr = u >> 7, cc = u & 127;
        qs[rr][cc] = q[(size_t)(bi * 16 + rr) * 128 + cc];
        ks[rr][cc] = kmat[(size_t)(bj * 16 + rr) * 128 + cc];
    }
    __syncthreads();
    int ty = tid >> 4, tx = tid & 15;
    const float4* qrow = reinterpret_cast<const float4*>(&qs[ty][0]);
    const float4* krow = reinterpret_cast<const float4*>(&ks[tx][0]);
    float acc = 0.f;
#pragma unroll
    for (int c4 = 0; c4 < 32; ++c4) {
        float4 a = qrow[c4], b = krow[c4];
        acc += a.x * b.x + a.y * b.y + a.z * b.z + a.w * b.w;
    }
    attn[(size_t)(bi * 16 + ty) * 2048 + (bj * 16 + tx)] = acc * 0.08838834764831845f;
}

// ---------------- softmax per row, in place; saves row 2047
__global__ __launch_bounds__(256) void softmax_kernel(
    float* __restrict__ attn, float* __restrict__ attnrow)
{
    int i = blockIdx.x, tid = threadIdx.x;
    float* row = attn + (size_t)i * 2048;
    __shared__ float red[256];
    float m = -1e30f;
    for (int j = tid; j < 2048; j += 256) m = fmaxf(m, row[j]);
    red[tid] = m; __syncthreads();
    for (int s = 128; s > 0; s >>= 1) { if (tid < s) red[tid] = fmaxf(red[tid], red[tid + s]); __syncthreads(); }
    m = red[0]; __syncthreads();
    float sum = 0.f;
    for (int j = tid; j < 2048; j += 256) sum += __expf(row[j] - m);
    red[tid] = sum; __syncthreads();
    for (int s = 128; s > 0; s >>= 1) { if (tid < s) red[tid] += red[tid + s]; __syncthreads(); }
    float inv = 1.f / red[0];
    for (int j = tid; j < 2048; j += 256) {
        float w = __expf(row[j] - m) * inv;
        row[j] = w;
        if (i == 2047) attnrow[j] = w;
    }
}

// ---------------- av[j] = sum_t attnrow[t] * v[t][j]
__global__ __launch_bounds__(128) void av_kernel(
    const float* __restrict__ attnrow, const float* __restrict__ v, float* __restrict__ av)
{
    int j = threadIdx.x;
    float acc = 0.f;
#pragma unroll 8
    for (int t = 0; t < 2048; ++t) acc += attnrow[t] * v[(size_t)t * 128 + j];
    av[j] = acc;
}

// ---------------- gmol = av @ Wfc.T + bfc -> feats[256..511]
__global__ __launch_bounds__(256) void gmolfc_kernel(
    const float* __restrict__ av, const float* __restrict__ Wfc, const float* __restrict__ bfc,
    float* __restrict__ feats)
{
    int o = threadIdx.x;
    __shared__ float a[128];
    if (o < 128) a[o] = av[o];
    __syncthreads();
    const float4* w4 = reinterpret_cast<const float4*>(Wfc + (size_t)o * 128);
    const float4* a4 = reinterpret_cast<const float4*>(a);
    float acc = bfc[o];
#pragma unroll 8
    for (int kk = 0; kk < 32; ++kk) {
        float4 w = w4[kk], x = a4[kk];
        acc += x.x * w.x + x.y * w.y + x.z * w.z + x.w * w.w;
    }
    feats[256 + o] = acc;
}

// ---------------- h1 = relu(agg1 @ W_gc1 + b), in place; Wt pre-transposed.
// Block = 8 nodes, 128 threads (o). Node rows read as wave-broadcast float4
// (L1-hot), W row per thread in registers per k4. VALU-bound.
__global__ __launch_bounds__(128) void gc1_kernel(
    float* __restrict__ agg1, const float* __restrict__ Wt, const float* __restrict__ b)
{
    int o = threadIdx.x;
    int n0 = blockIdx.x * 8;
    const float4* wrow = reinterpret_cast<const float4*>(Wt + (size_t)o * 128);
    const float4* r4 = reinterpret_cast<const float4*>(agg1 + (size_t)n0 * 128);
    float acc[8];
    float bias = b[o];
#pragma unroll
    for (int n = 0; n < 8; ++n) acc[n] = bias;
    for (int k4 = 0; k4 < 32; ++k4) {
        float4 w = wrow[k4];
#pragma unroll
        for (int n = 0; n < 8; ++n) {
            float4 rv = r4[n * 32 + k4];
            acc[n] += rv.x * w.x + rv.y * w.y + rv.z * w.z + rv.w * w.w;
        }
    }
    __syncthreads();   // all reads of these 8 rows done before in-place writes
#pragma unroll
    for (int n = 0; n < 8; ++n)
        agg1[(size_t)(n0 + n) * 128 + o] = fmaxf(acc[n], 0.f);
}

// ---------------- gsum[j] = sum_e ew[e] * h1[src[e]][j]
__global__ __launch_bounds__(256) void wsum_kernel(
    const float* __restrict__ h1g, const float* __restrict__ ew,
    const int* __restrict__ esrc, float* __restrict__ gsum)
{
    int j = threadIdx.x & 127, half = threadIdx.x >> 7;
    float acc = 0.f;
    for (int e = blockIdx.x * 2 + half; e < NEDGE; e += gridDim.x * 2)
        acc += ew[e] * h1g[(size_t)esrc[e] * 128 + j];
    __shared__ float red[256];
    red[threadIdx.x] = acc;
    __syncthreads();
    if (threadIdx.x < 128) atomicAdd(gsum + j, red[j] + red[j + 128]);
}

// ---------------- feats: hg (=(gsum/N)@W_gc2+b_gc2) + smiles + kmer
__global__ __launch_bounds__(256) void feats_kernel(
    const float* __restrict__ gsum, const float* __restrict__ W_gc2, const float* __restrict__ b_gc2,
    const float* __restrict__ smiles, const float* __restrict__ kmer, float* __restrict__ feats)
{
    int i = blockIdx.x * 256 + threadIdx.x;
    if (i < 256) {
        float dotv = 0.f;
#pragma unroll 4
        for (int k = 0; k < 128; ++k) dotv += gsum[k] * W_gc2[(size_t)k * 256 + i];
        feats[i] = b_gc2[i] + dotv * (1.f / (float)NNODE);
    } else if (i >= 512 && i < 1086) {
        feats[i] = smiles[i - 512];
    } else if (i >= 1086 && i < 1150) {
        feats[i] = kmer[i - 1086];
    }
}

// ---------------- MLP: layer 1 (1150->575), one block per output
__global__ __launch_bounds__(256) void mlp1_kernel(
    const float* __restrict__ feats, const float* __restrict__ W1, const float* __restrict__ b1,
    float* __restrict__ f1)
{
    int o = blockIdx.x, tid = threadIdx.x;
    const float* w = W1 + (size_t)o * 1150;
    float acc = 0.f;
    for (int k = tid; k < 1150; k += 256) acc += feats[k] * w[k];
    __shared__ float red[256];
    red[tid] = acc; __syncthreads();
    for (int s = 128; s > 0; s >>= 1) { if (tid < s) red[tid] += red[tid + s]; __syncthreads(); }
    if (tid == 0) f1[o] = fmaxf(red[0] + b1[o], 0.f);
}

// ---------------- MLP: layer 2 (575->256), one block per output
__global__ __launch_bounds__(256) void mlp2_kernel(
    const float* __restrict__ f1, const float* __restrict__ W2, const float* __restrict__ b2,
    float* __restrict__ f2)
{
    int o = blockIdx.x, tid = threadIdx.x;
    const float* w = W2 + (size_t)o * 575;
    float acc = 0.f;
    for (int k = tid; k < 575; k += 256) acc += f1[k] * w[k];
    __shared__ float red[256];
    red[tid] = acc; __syncthreads();
    for (int s = 128; s > 0; s >>= 1) { if (tid < s) red[tid] += red[tid + s]; __syncthreads(); }
    if (tid == 0) f2[o] = fmaxf(red[0] + b2[o], 0.f);
}

// ---------------- MLP: layers 3+4 (256->64->1)
__global__ __launch_bounds__(256) void mlp_tail_kernel(
    const float* __restrict__ f2,
    const float* __restrict__ W3, const float* __restrict__ b3,
    const float* __restrict__ W4, const float* __restrict__ b4,
    float* __restrict__ out)
{
    __shared__ float f2s[256];
    __shared__ float f3[64];
    int tid = threadIdx.x;
    f2s[tid] = f2[tid];
    __syncthreads();
    if (tid < 64) {
        const float* w = W3 + (size_t)tid * 256;
        float acc = b3[tid];
        for (int k = 0; k < 256; ++k) acc += f2s[k] * w[k];
        f3[tid] = fmaxf(acc, 0.f);
    }
    __syncthreads();
    if (tid == 0) {
        float acc = b4[0];
        for (int k = 0; k < 64; ++k) acc += f3[k] * W4[k];
        out[0] = acc;
    }
}

// ---------------------------------------------------------------------------
extern "C" void kernel_launch(void* const* d_in, const int* in_sizes, int n_in,
                              void* d_out, int out_size, void* d_ws, size_t ws_size,
                              hipStream_t stream)
{
    const float* g_mol   = (const float*)d_in[0];
    const float* feat_seq= (const float*)d_in[1];
    const float* smiles  = (const float*)d_in[2];
    const float* kmer    = (const float*)d_in[3];
    const float* edge_w  = (const float*)d_in[4];
    const float* w_ih0   = (const float*)d_in[5];
    const float* w_hh0   = (const float*)d_in[6];
    const float* b_ih0   = (const float*)d_in[7];
    const float* b_hh0   = (const float*)d_in[8];
    const float* w_ih1   = (const float*)d_in[9];
    const float* w_hh1   = (const float*)d_in[10];
    const float* b_ih1   = (const float*)d_in[11];
    const float* b_hh1   = (const float*)d_in[12];
    const float* Wq      = (const float*)d_in[13];
    const float* bq      = (const float*)d_in[14];
    const float* Wk      = (const float*)d_in[15];
    const float* bk      = (const float*)d_in[16];
    const float* Wv      = (const float*)d_in[17];
    const float* bv      = (const float*)d_in[18];
    const float* Wfc     = (const float*)d_in[19];
    const float* bfc     = (const float*)d_in[20];
    const float* W_gc1   = (const float*)d_in[21];
    const float* b_gc1   = (const float*)d_in[22];
    const float* W_gc2   = (const float*)d_in[23];
    const float* b_gc2   = (const float*)d_in[24];
    const float* W1      = (const float*)d_in[25];
    const float* b1      = (const float*)d_in[26];
    const float* W2      = (const float*)d_in[27];
    const float* b2      = (const float*)d_in[28];
    const float* W3      = (const float*)d_in[29];
    const float* b3      = (const float*)d_in[30];
    const float* W4      = (const float*)d_in[31];
    const float* b4      = (const float*)d_in[32];
    const int* esrc      = (const int*)d_in[33];
    const int* edst      = (const int*)d_in[34];

    float* ws    = (float*)d_ws;
    float* xg    = ws + OFF_XG;
    float* h0    = ws + OFF_H0;
    float* h1    = ws + OFF_H1;
    float* q     = ws + OFF_Q;
    float* k     = ws + OFF_K;
    float* v     = ws + OFF_V;
    float* arow  = ws + OFF_AROW;
    float* av    = ws + OFF_AV;
    float* feats = ws + OFF_FEATS;
    float* f1    = ws + OFF_F1;
    float* f2    = ws + OFF_F2;
    float* gsum  = ws + OFF_GSUM;
    float* agg1  = ws + OFF_AGG1;
    uint32_t* wpk= (uint32_t*)(ws + OFF_WPK);
    float* Wt1   = ws + OFF_WT1;

    float* out_f = (float*)d_out;
    float* attn  = out_f + 1;   // [2048][2048], scores then softmax in place

    // zero GNN accumulators (gsum + agg1 contiguous)
    hipMemsetAsync(gsum, 0, (size_t)(128 + (size_t)NNODE * 128) * sizeof(float), stream);

    // one-time weight prep (packed fp16 w_hh, transposed W_gc1)
    prep_kernel<<<576, 256, 0, stream>>>(w_hh0, w_hh1, W_gc1, wpk, Wt1);

    // ---- layer 0: input proj, then recurrence fused with edge scatter ----
    xg0_kernel<<<4096, 512, 0, stream>>>(g_mol, w_ih0, b_ih0, b_hh0, xg);
    lstm_fused_kernel<<<2 + 510, 512, 0, stream>>>(
        xg, wpk, h0, feat_seq, edge_w, esrc, edst, agg1, 1);

    // ---- layer 1 ----
    xg1_kernel<<<256, 512, 0, stream>>>(h0, w_ih1, b_ih1, b_hh1, xg);
    lstm_fused_kernel<<<2, 512, 0, stream>>>(
        xg, wpk + 65536, h1, feat_seq, edge_w, esrc, edst, agg1, 0);

    // ---- GCN tail (scatter finished in layer-0 launch) ----
    gc1_kernel<<<NNODE / 8, 128, 0, stream>>>(agg1, Wt1, b_gc1);
    wsum_kernel<<<2048, 256, 0, stream>>>(agg1, edge_w, esrc, gsum);
    feats_kernel<<<5, 256, 0, stream>>>(gsum, W_gc2, b_gc2, smiles, kmer, feats);

    // ---- attention ----
    qkv_kernel<<<2048, 384, 0, stream>>>(h1, Wq, bq, Wk, bk, Wv, bv, q, k, v);
    scores_kernel<<<dim3(128, 128), 256, 0, stream>>>(q, k, attn);
    softmax_kernel<<<2048, 256, 0, stream>>>(attn, arow);
    av_kernel<<<1, 128, 0, stream>>>(arow, v, av);
    gmolfc_kernel<<<1, 256, 0, stream>>>(av, Wfc, bfc, feats);

    // ---- head ----
    mlp1_kernel<<<575, 256, 0, stream>>>(feats, W1, b1, f1);
    mlp2_kernel<<<256, 256, 0, stream>>>(f1, W2, b2, f2);
    mlp_tail_kernel<<<1, 256, 0, stream>>>(f2, W3, b3, W4, b4, out_f);
}

// Round 4
// 3301.523 us; speedup vs baseline: 1.6068x; 1.2497x over previous
//
#include <hip/hip_runtime.h>
#include <stdint.h>

// ---------------------------------------------------------------------------
// EMMPTNet: 2-layer bidir LSTM (T=2048,H=128) -> self-attn (attn matrix is
// output 1) -> 2-hop GCN (50k nodes, 600k edges) -> MLP (output 0).
// fp32 I/O. LSTM recurrent matvec: packed fp16 + v_dot2 (fp32 accumulate).
// GCN: CSR gather (no fp32 scatter atomics); gsum = sum_n outw[n]*h1[n].
// ---------------------------------------------------------------------------

#define T_SEQ 2048
#define NNODE 50000
#define NEDGE 600000

typedef _Float16 half2_t __attribute__((ext_vector_type(2)));

static __device__ __forceinline__ float sigf(float x) { return 1.f / (1.f + __expf(-x)); }
static __device__ __forceinline__ float tanh_fast(float x) { return 1.f - 2.f / (1.f + __expf(2.f * x)); }

static __device__ __forceinline__ float dot2h(float acc, uint32_t a, uint32_t b) {
#if __has_builtin(__builtin_amdgcn_fdot2)
    return __builtin_amdgcn_fdot2(__builtin_bit_cast(half2_t, a),
                                  __builtin_bit_cast(half2_t, b), acc, false);
#else
    half2_t ha = __builtin_bit_cast(half2_t, a);
    half2_t hb = __builtin_bit_cast(half2_t, b);
    return acc + (float)ha.x * (float)hb.x + (float)ha.y * (float)hb.y;
#endif
}

// ---------------- workspace layout (4-byte word offsets) ----------------
constexpr size_t OFF_XGT   = 0;                      // [1024][2048] xg transposed (shared L0/L1)
constexpr size_t OFF_HT0   = OFF_XGT + 2097152;      // [256][2048] h0 transposed
constexpr size_t OFF_HT1   = OFF_HT0 + 524288;       // [256][2048] h1 transposed
constexpr size_t OFF_Q     = OFF_HT1 + 524288;       // [2048][128]
constexpr size_t OFF_K     = OFF_Q + 262144;
constexpr size_t OFF_V     = OFF_K + 262144;
constexpr size_t OFF_AROW  = OFF_V + 262144;         // [2048]
constexpr size_t OFF_AV    = OFF_AROW + 2048;        // [128]
constexpr size_t OFF_FEATS = OFF_AV + 128;           // [1152]
constexpr size_t OFF_F1    = OFF_FEATS + 1152;       // [576]
constexpr size_t OFF_F2    = OFF_F1 + 576;           // [256]
constexpr size_t OFF_GSUM  = OFF_F2 + 256;           // [128]   (memset group start)
constexpr size_t OFF_OUTW  = OFF_GSUM + 128;         // [50000] fp32
constexpr size_t OFF_DEG   = OFF_OUTW + 50000;       // [50000] int (memset group end)
constexpr size_t OFF_ROWP  = OFF_DEG + 50000;        // [50000] int
constexpr size_t OFF_CUR   = OFF_ROWP + 50000;       // [50000] int
constexpr size_t OFF_WPK   = OFF_CUR + 50000;        // [131072] u32 packed fp16 w_hh
constexpr size_t OFF_EPACK = OFF_WPK + 131072;       // [600000] uint2
constexpr size_t WS_WORDS  = OFF_EPACK + 1200000;    // ~21.9 MB

// ---------------- one-time prep: pack w_hh (both layers) to fp16 pairs.
// wpk u32 index (per layer): ((dg*128 + l)*4 + m)*16 + kk,  dg = dir*4+g,
// value = half2( w[dir][m*128+l][32g+2kk], w[dir][m*128+l][32g+2kk+1] )
__global__ __launch_bounds__(256) void prep_kernel(
    const float* __restrict__ w_hh0, const float* __restrict__ w_hh1,
    uint32_t* __restrict__ wpk)
{
    int i = blockIdx.x * 256 + threadIdx.x;
    if (i >= 131072) return;
    int layer = i >> 16;
    int r = i & 65535;
    int kk = r & 15, m = (r >> 4) & 3, l = (r >> 6) & 127, dg = r >> 13;
    int dirv = dg >> 2, gg = dg & 3;
    const float* w = layer ? w_hh1 : w_hh0;
    const float* row = w + ((size_t)dirv * 512 + m * 128 + l) * 128;
    int k0 = gg * 32 + kk * 2;
    half2_t hv;
    hv.x = (_Float16)row[k0];
    hv.y = (_Float16)row[k0 + 1];
    wpk[i] = __builtin_bit_cast(uint32_t, hv);
}

// ---------------- layer-0 input projection -> xgT[row][t] (biases folded)
__global__ __launch_bounds__(512) void xg0_kernel(
    const float* __restrict__ g_mol, const float* __restrict__ w_ih,
    const float* __restrict__ b_ih, const float* __restrict__ b_hh,
    float* __restrict__ xgT)
{
    int b = blockIdx.x;
    int dir = b >> 7, t0 = (b & 127) * 16;
    int r = threadIdx.x;
    __shared__ float xs[272];                 // 16 rows x 17, contiguous in g_mol
    if (r < 272) xs[r] = g_mol[t0 * 17 + r];
    __syncthreads();
    const float* wrow = w_ih + (size_t)(dir * 512 + r) * 17;
    float wv[17];
#pragma unroll
    for (int k = 0; k < 17; ++k) wv[k] = wrow[k];
    float bias = b_ih[dir * 512 + r] + b_hh[dir * 512 + r];
    float acc[16];
#pragma unroll
    for (int tt = 0; tt < 16; ++tt) {
        float a = bias;
#pragma unroll
        for (int k = 0; k < 17; ++k) a += xs[tt * 17 + k] * wv[k];
        acc[tt] = a;
    }
    float* orow = xgT + (size_t)(dir * 512 + r) * 2048 + t0;
    *(float4*)(orow + 0)  = make_float4(acc[0], acc[1], acc[2], acc[3]);
    *(float4*)(orow + 4)  = make_float4(acc[4], acc[5], acc[6], acc[7]);
    *(float4*)(orow + 8)  = make_float4(acc[8], acc[9], acc[10], acc[11]);
    *(float4*)(orow + 12) = make_float4(acc[12], acc[13], acc[14], acc[15]);
}

// ---------------- layer-1 input projection: hT0 -> xgT[row][t]
__global__ __launch_bounds__(512) void xg1_kernel(
    const float* __restrict__ hT0, const float* __restrict__ w_ih,
    const float* __restrict__ b_ih, const float* __restrict__ b_hh,
    float* __restrict__ xgT)
{
    int b = blockIdx.x;
    int dir = b >> 7, t0 = (b & 127) * 16;
    int tid = threadIdx.x;
    __shared__ float xs[16 * 256];            // [tt][k]
    for (int u = tid; u < 1024; u += 512) {
        int k = u >> 2, j4 = u & 3;
        float4 v = *(const float4*)(hT0 + (size_t)k * 2048 + t0 + 4 * j4);
        xs[(4 * j4 + 0) * 256 + k] = v.x;
        xs[(4 * j4 + 1) * 256 + k] = v.y;
        xs[(4 * j4 + 2) * 256 + k] = v.z;
        xs[(4 * j4 + 3) * 256 + k] = v.w;
    }
    __syncthreads();
    int r = tid;
    float bias = b_ih[dir * 512 + r] + b_hh[dir * 512 + r];
    float acc[16];
#pragma unroll
    for (int tt = 0; tt < 16; ++tt) acc[tt] = bias;
    const float4* w4 = reinterpret_cast<const float4*>(w_ih + (size_t)(dir * 512 + r) * 256);
    const float4* xs4 = reinterpret_cast<const float4*>(xs);
    for (int k4 = 0; k4 < 64; ++k4) {
        float4 w = w4[k4];
#pragma unroll
        for (int tt = 0; tt < 16; ++tt) {
            float4 x = xs4[tt * 64 + k4];
            acc[tt] += x.x * w.x + x.y * w.y + x.z * w.z + x.w * w.w;
        }
    }
    float* orow = xgT + (size_t)(dir * 512 + r) * 2048 + t0;
    *(float4*)(orow + 0)  = make_float4(acc[0], acc[1], acc[2], acc[3]);
    *(float4*)(orow + 4)  = make_float4(acc[4], acc[5], acc[6], acc[7]);
    *(float4*)(orow + 8)  = make_float4(acc[8], acc[9], acc[10], acc[11]);
    *(float4*)(orow + 12) = make_float4(acc[12], acc[13], acc[14], acc[15]);
}

// ---------------- unified fused kernel: blocks 0,1 = LSTM recurrence; blocks
// >=2 = side work (mode 0: edge histogram + outw; mode 1: CSR gather GNN).
__global__ __launch_bounds__(512, 2) void lstm_fused_kernel(
    const float* __restrict__ xgT, const uint32_t* __restrict__ wpk,
    float* __restrict__ hT, int mode,
    const int* __restrict__ esrc, const int* __restrict__ edst,
    const float* __restrict__ ew,
    int* __restrict__ deg, float* __restrict__ outw,
    const int* __restrict__ rowp, const uint2* __restrict__ epack,
    const float* __restrict__ feat_seq,
    const float* __restrict__ Wgc1, const float* __restrict__ bgc1,
    float* __restrict__ gsum)
{
    __shared__ __align__(16) float smem[17664];
    const int tid = threadIdx.x;

    if (blockIdx.x >= 2) {
        if (mode == 0) {
            // edge histogram (in-degree) + per-src weight sums
            int stride = (gridDim.x - 2) * 512;
            for (int e = (blockIdx.x - 2) * 512 + tid; e < NEDGE; e += stride) {
                atomicAdd(&deg[edst[e]], 1);
                atomicAdd(&outw[esrc[e]], ew[e]);
            }
        } else {
            // CSR gather: per node, agg1 row -> relu(agg1@W+b) -> gsum += outw[n]*h1
            float* wt   = smem;            // 16384 = W_gc1 [k][o]
            float* bg   = smem + 16384;    // 128
            float* aggl = smem + 16512;    // 8 waves x 128
            float* gbuf = smem + 17536;    // 128
            {
                float4* d4 = (float4*)wt;
                const float4* s4 = (const float4*)Wgc1;
                for (int u = tid; u < 4096; u += 512) d4[u] = s4[u];
                if (tid < 128) { bg[tid] = bgc1[tid]; gbuf[tid] = 0.f; }
            }
            __syncthreads();
            int wv = tid >> 6, lane = tid & 63;
            float ga0 = 0.f, ga1 = 0.f;
            int nwaves = (gridDim.x - 2) * 8;
            for (int n = (blockIdx.x - 2) * 8 + wv; n < NNODE; n += nwaves) {
                int st = rowp[n];
                int dg = deg[n];
                float a0 = 0.f, a1 = 0.f;
                for (int i = 0; i < dg; ++i) {
                    uint2 ep = epack[st + i];
                    float w = __uint_as_float(ep.y);
                    float2 f = *(const float2*)(feat_seq + (size_t)ep.x * 128 + 2 * lane);
                    a0 += w * f.x;
                    a1 += w * f.y;
                }
                *(float2*)&aggl[wv * 128 + 2 * lane] = make_float2(a0, a1);
                float h0 = bg[2 * lane], h1v = bg[2 * lane + 1];
                for (int k = 0; k < 128; ++k) {
                    float av_ = aggl[wv * 128 + k];
                    float2 wv2 = *(const float2*)&wt[k * 128 + 2 * lane];
                    h0 += av_ * wv2.x;
                    h1v += av_ * wv2.y;
                }
                float ow = outw[n];
                ga0 += ow * fmaxf(h0, 0.f);
                ga1 += ow * fmaxf(h1v, 0.f);
            }
            atomicAdd(&gbuf[2 * lane], ga0);
            atomicAdd(&gbuf[2 * lane + 1], ga1);
            __syncthreads();
            if (tid < 128) atomicAdd(&gsum[tid], gbuf[tid]);
        }
        return;
    }

    // ---------------- LSTM recurrence (blocks 0,1 = directions) ----------------
#if __has_builtin(__builtin_amdgcn_s_setprio)
    __builtin_amdgcn_s_setprio(3);
#endif
    const int dir = blockIdx.x;
    const int g = tid >> 7;
    const int l = tid & 127;

    _Float16* h_half = reinterpret_cast<_Float16*>(smem);   // 128 halfs
    float* pbuf = smem + 64;                                 // 128 x 20 (pad)

    const uint4* wt4 = reinterpret_cast<const uint4*>(
        wpk + ((size_t)((dir * 4 + g) * 128 + l)) * 64);
    uint32_t wr[4][16];
#pragma unroll
    for (int m = 0; m < 4; ++m)
#pragma unroll
        for (int j = 0; j < 4; ++j) {
            uint4 wv = wt4[m * 4 + j];
            wr[m][4 * j + 0] = wv.x; wr[m][4 * j + 1] = wv.y;
            wr[m][4 * j + 2] = wv.z; wr[m][4 * j + 3] = wv.w;
        }

    if (tid < 128) h_half[tid] = (_Float16)0.f;
    float c = 0.f;
    float hq[16];
    __syncthreads();

    const float* xrow = xgT + (size_t)(dir * 512 + tid) * 2048;
    float* hrow = hT + (size_t)(dir * 128 + l) * 2048;
    const uint4* h4 = reinterpret_cast<const uint4*>(h_half);

    for (int s16 = 0; s16 < 128; ++s16) {
        const int base = dir ? (2032 - s16 * 16) : (s16 * 16);
        float4 A  = *(const float4*)(xrow + base);
        float4 B4 = *(const float4*)(xrow + base + 4);
        float4 C4 = *(const float4*)(xrow + base + 8);
        float4 D4 = *(const float4*)(xrow + base + 12);
        float xq[16];
        if (dir) {
            xq[0]=D4.w;  xq[1]=D4.z;  xq[2]=D4.y;  xq[3]=D4.x;
            xq[4]=C4.w;  xq[5]=C4.z;  xq[6]=C4.y;  xq[7]=C4.x;
            xq[8]=B4.w;  xq[9]=B4.z;  xq[10]=B4.y; xq[11]=B4.x;
            xq[12]=A.w;  xq[13]=A.z;  xq[14]=A.y;  xq[15]=A.x;
        } else {
            xq[0]=A.x;   xq[1]=A.y;   xq[2]=A.z;   xq[3]=A.w;
            xq[4]=B4.x;  xq[5]=B4.y;  xq[6]=B4.z;  xq[7]=B4.w;
            xq[8]=C4.x;  xq[9]=C4.y;  xq[10]=C4.z; xq[11]=C4.w;
            xq[12]=D4.x; xq[13]=D4.y; xq[14]=D4.z; xq[15]=D4.w;
        }
#pragma unroll
        for (int i = 0; i < 16; ++i) {
            // phase A: matvec partials over k-chunk g; fold xg into gate m==g
            float a0 = (g == 0) ? xq[i] : 0.f;
            float a1 = (g == 1) ? xq[i] : 0.f;
            float a2 = (g == 2) ? xq[i] : 0.f;
            float a3 = (g == 3) ? xq[i] : 0.f;
#pragma unroll
            for (int q = 0; q < 4; ++q) {
                uint4 hv = h4[g * 4 + q];       // broadcast read
                a0 = dot2h(a0, hv.x, wr[0][4 * q + 0]);
                a0 = dot2h(a0, hv.y, wr[0][4 * q + 1]);
                a0 = dot2h(a0, hv.z, wr[0][4 * q + 2]);
                a0 = dot2h(a0, hv.w, wr[0][4 * q + 3]);
                a1 = dot2h(a1, hv.x, wr[1][4 * q + 0]);
                a1 = dot2h(a1, hv.y, wr[1][4 * q + 1]);
                a1 = dot2h(a1, hv.z, wr[1][4 * q + 2]);
                a1 = dot2h(a1, hv.w, wr[1][4 * q + 3]);
                a2 = dot2h(a2, hv.x, wr[2][4 * q + 0]);
                a2 = dot2h(a2, hv.y, wr[2][4 * q + 1]);
                a2 = dot2h(a2, hv.z, wr[2][4 * q + 2]);
                a2 = dot2h(a2, hv.w, wr[2][4 * q + 3]);
                a3 = dot2h(a3, hv.x, wr[3][4 * q + 0]);
                a3 = dot2h(a3, hv.y, wr[3][4 * q + 1]);
                a3 = dot2h(a3, hv.z, wr[3][4 * q + 2]);
                a3 = dot2h(a3, hv.w, wr[3][4 * q + 3]);
            }
            *(float4*)&pbuf[l * 20 + 4 * g] = make_float4(a0, a1, a2, a3);
            __syncthreads();

            // phase B: lanes 0..127 reduce 4 chunks, activate, update c/h
            if (tid < 128) {
                float4 v0 = *(float4*)&pbuf[l * 20];
                float4 v1 = *(float4*)&pbuf[l * 20 + 4];
                float4 v2 = *(float4*)&pbuf[l * 20 + 8];
                float4 v3 = *(float4*)&pbuf[l * 20 + 12];
                float pi = v0.x + v1.x + v2.x + v3.x;
                float pf = v0.y + v1.y + v2.y + v3.y;
                float pg = v0.z + v1.z + v2.z + v3.z;
                float po = v0.w + v1.w + v2.w + v3.w;
                float iv = sigf(pi), fv = sigf(pf);
                float gv = tanh_fast(pg), ov = sigf(po);
                c = fv * c + iv * gv;
                float hv = ov * tanh_fast(c);
                h_half[l] = (_Float16)hv;
                if (dir) hq[15 - i] = hv; else hq[i] = hv;
            }
            __syncthreads();
        }
        if (tid < 128) {
            *(float4*)(hrow + base + 0)  = make_float4(hq[0], hq[1], hq[2], hq[3]);
            *(float4*)(hrow + base + 4)  = make_float4(hq[4], hq[5], hq[6], hq[7]);
            *(float4*)(hrow + base + 8)  = make_float4(hq[8], hq[9], hq[10], hq[11]);
            *(float4*)(hrow + base + 12) = make_float4(hq[12], hq[13], hq[14], hq[15]);
        }
    }
}

// ---------------- CSR scan: deg -> rowp (exclusive), cursor copy
__global__ __launch_bounds__(1024) void scan_kernel(
    const int* __restrict__ deg, int* __restrict__ rowp, int* __restrict__ cur)
{
    __shared__ int part[1024];
    int t = threadIdx.x;
    int lo = t * 49, hi = min(lo + 49, NNODE);
    int s = 0;
    for (int i = lo; i < hi; ++i) s += deg[i];
    part[t] = s;
    __syncthreads();
    for (int off = 1; off < 1024; off <<= 1) {
        int v = (t >= off) ? part[t - off] : 0;
        __syncthreads();
        part[t] += v;
        __syncthreads();
    }
    int run = t ? part[t - 1] : 0;
    for (int i = lo; i < hi; ++i) {
        rowp[i] = run;
        cur[i] = run;
        run += deg[i];
    }
}

// ---------------- CSR fill: epack[pos] = {src, weight}
__global__ __launch_bounds__(512) void fill_kernel(
    const int* __restrict__ esrc, const int* __restrict__ edst,
    const float* __restrict__ ew, int* __restrict__ cur,
    uint2* __restrict__ epack)
{
    int e = blockIdx.x * 512 + threadIdx.x;
    if (e >= NEDGE) return;
    int d = edst[e];
    int pos = atomicAdd(&cur[d], 1);
    epack[pos] = make_uint2((unsigned)esrc[e], __float_as_uint(ew[e]));
}

// ---------------- q/k/v projection from hT1, 16 timesteps per block
__global__ __launch_bounds__(384) void qkv_kernel(
    const float* __restrict__ hT1,
    const float* __restrict__ Wq, const float* __restrict__ bq,
    const float* __restrict__ Wk, const float* __restrict__ bk,
    const float* __restrict__ Wv, const float* __restrict__ bv,
    float* __restrict__ q, float* __restrict__ k, float* __restrict__ v)
{
    int t0 = blockIdx.x * 16, tid = threadIdx.x;
    __shared__ float xs[16 * 256];
    for (int u = tid; u < 1024; u += 384) {
        int kk = u >> 2, j4 = u & 3;
        float4 vv = *(const float4*)(hT1 + (size_t)kk * 2048 + t0 + 4 * j4);
        xs[(4 * j4 + 0) * 256 + kk] = vv.x;
        xs[(4 * j4 + 1) * 256 + kk] = vv.y;
        xs[(4 * j4 + 2) * 256 + kk] = vv.z;
        xs[(4 * j4 + 3) * 256 + kk] = vv.w;
    }
    __syncthreads();
    int which = tid >> 7, j = tid & 127;
    const float* W = (which == 0) ? Wq : (which == 1) ? Wk : Wv;
    const float* B = (which == 0) ? bq : (which == 1) ? bk : bv;
    float* out = (which == 0) ? q : (which == 1) ? k : v;
    float bias = B[j];
    float acc[16];
#pragma unroll
    for (int tt = 0; tt < 16; ++tt) acc[tt] = bias;
    const float4* w4 = reinterpret_cast<const float4*>(W + (size_t)j * 256);
    const float4* xs4 = reinterpret_cast<const float4*>(xs);
    for (int k4 = 0; k4 < 64; ++k4) {
        float4 w = w4[k4];
#pragma unroll
        for (int tt = 0; tt < 16; ++tt) {
            float4 x = xs4[tt * 64 + k4];
            acc[tt] += x.x * w.x + x.y * w.y + x.z * w.z + x.w * w.w;
        }
    }
#pragma unroll
    for (int tt = 0; tt < 16; ++tt) out[(size_t)(t0 + tt) * 128 + j] = acc[tt];
}

// ---------------- scores = q @ k.T / sqrt(128), straight into d_out+1
__global__ __launch_bounds__(256) void scores_kernel(
    const float* __restrict__ q, const float* __restrict__ kmat, float* __restrict__ attn)
{
    int bi = blockIdx.y, bj = blockIdx.x, tid = threadIdx.x;
    __shared__ float qs[16][132];
    __shared__ float ks[16][132];
    for (int u = tid; u < 2048; u += 256) {
        int rr = u >> 7, cc = u & 127;
        qs[rr][cc] = q[(size_t)(bi * 16 + rr) * 128 + cc];
        ks[rr][cc] = kmat[(size_t)(bj * 16 + rr) * 128 + cc];
    }
    __syncthreads();
    int ty = tid >> 4, tx = tid & 15;
    const float4* qrow = reinterpret_cast<const float4*>(&qs[ty][0]);
    const float4* krow = reinterpret_cast<const float4*>(&ks[tx][0]);
    float acc = 0.f;
#pragma unroll
    for (int c4 = 0; c4 < 32; ++c4) {
        float4 a = qrow[c4], b = krow[c4];
        acc += a.x * b.x + a.y * b.y + a.z * b.z + a.w * b.w;
    }
    attn[(size_t)(bi * 16 + ty) * 2048 + (bj * 16 + tx)] = acc * 0.08838834764831845f;
}

// ---------------- softmax per row, in place; saves row 2047
__global__ __launch_bounds__(256) void softmax_kernel(
    float* __restrict__ attn, float* __restrict__ attnrow)
{
    int i = blockIdx.x, tid = threadIdx.x;
    float* row = attn + (size_t)i * 2048;
    __shared__ float red[256];
    float m = -1e30f;
    for (int j = tid; j < 2048; j += 256) m = fmaxf(m, row[j]);
    red[tid] = m; __syncthreads();
    for (int s = 128; s > 0; s >>= 1) { if (tid < s) red[tid] = fmaxf(red[tid], red[tid + s]); __syncthreads(); }
    m = red[0]; __syncthreads();
    float sum = 0.f;
    for (int j = tid; j < 2048; j += 256) sum += __expf(row[j] - m);
    red[tid] = sum; __syncthreads();
    for (int s = 128; s > 0; s >>= 1) { if (tid < s) red[tid] += red[tid + s]; __syncthreads(); }
    float inv = 1.f / red[0];
    for (int j = tid; j < 2048; j += 256) {
        float w = __expf(row[j] - m) * inv;
        row[j] = w;
        if (i == 2047) attnrow[j] = w;
    }
}

// ---------------- av[j] = sum_t attnrow[t] * v[t][j]
__global__ __launch_bounds__(128) void av_kernel(
    const float* __restrict__ attnrow, const float* __restrict__ v, float* __restrict__ av)
{
    int j = threadIdx.x;
    float acc = 0.f;
#pragma unroll 8
    for (int t = 0; t < 2048; ++t) acc += attnrow[t] * v[(size_t)t * 128 + j];
    av[j] = acc;
}

// ---------------- gmol = av @ Wfc.T + bfc -> feats[256..511]
__global__ __launch_bounds__(256) void gmolfc_kernel(
    const float* __restrict__ av, const float* __restrict__ Wfc, const float* __restrict__ bfc,
    float* __restrict__ feats)
{
    int o = threadIdx.x;
    __shared__ float a[128];
    if (o < 128) a[o] = av[o];
    __syncthreads();
    const float4* w4 = reinterpret_cast<const float4*>(Wfc + (size_t)o * 128);
    const float4* a4 = reinterpret_cast<const float4*>(a);
    float acc = bfc[o];
#pragma unroll 8
    for (int kk = 0; kk < 32; ++kk) {
        float4 w = w4[kk], x = a4[kk];
        acc += x.x * w.x + x.y * w.y + x.z * w.z + x.w * w.w;
    }
    feats[256 + o] = acc;
}

// ---------------- feats: hg (=(gsum/N)@W_gc2+b_gc2) + smiles + kmer
__global__ __launch_bounds__(256) void feats_kernel(
    const float* __restrict__ gsum, const float* __restrict__ W_gc2, const float* __restrict__ b_gc2,
    const float* __restrict__ smiles, const float* __restrict__ kmer, float* __restrict__ feats)
{
    int i = blockIdx.x * 256 + threadIdx.x;
    if (i < 256) {
        float dotv = 0.f;
#pragma unroll 4
        for (int k = 0; k < 128; ++k) dotv += gsum[k] * W_gc2[(size_t)k * 256 + i];
        feats[i] = b_gc2[i] + dotv * (1.f / (float)NNODE);
    } else if (i >= 512 && i < 1086) {
        feats[i] = smiles[i - 512];
    } else if (i >= 1086 && i < 1150) {
        feats[i] = kmer[i - 1086];
    }
}

// ---------------- MLP layers
__global__ __launch_bounds__(256) void mlp1_kernel(
    const float* __restrict__ feats, const float* __restrict__ W1, const float* __restrict__ b1,
    float* __restrict__ f1)
{
    int o = blockIdx.x, tid = threadIdx.x;
    const float* w = W1 + (size_t)o * 1150;
    float acc = 0.f;
    for (int k = tid; k < 1150; k += 256) acc += feats[k] * w[k];
    __shared__ float red[256];
    red[tid] = acc; __syncthreads();
    for (int s = 128; s > 0; s >>= 1) { if (tid < s) red[tid] += red[tid + s]; __syncthreads(); }
    if (tid == 0) f1[o] = fmaxf(red[0] + b1[o], 0.f);
}

__global__ __launch_bounds__(256) void mlp2_kernel(
    const float* __restrict__ f1, const float* __restrict__ W2, const float* __restrict__ b2,
    float* __restrict__ f2)
{
    int o = blockIdx.x, tid = threadIdx.x;
    const float* w = W2 + (size_t)o * 575;
    float acc = 0.f;
    for (int k = tid; k < 575; k += 256) acc += f1[k] * w[k];
    __shared__ float red[256];
    red[tid] = acc; __syncthreads();
    for (int s = 128; s > 0; s >>= 1) { if (tid < s) red[tid] += red[tid + s]; __syncthreads(); }
    if (tid == 0) f2[o] = fmaxf(red[0] + b2[o], 0.f);
}

__global__ __launch_bounds__(256) void mlp_tail_kernel(
    const float* __restrict__ f2,
    const float* __restrict__ W3, const float* __restrict__ b3,
    const float* __restrict__ W4, const float* __restrict__ b4,
    float* __restrict__ out)
{
    __shared__ float f2s[256];
    __shared__ float f3[64];
    int tid = threadIdx.x;
    f2s[tid] = f2[tid];
    __syncthreads();
    if (tid < 64) {
        const float* w = W3 + (size_t)tid * 256;
        float acc = b3[tid];
        for (int k = 0; k < 256; ++k) acc += f2s[k] * w[k];
        f3[tid] = fmaxf(acc, 0.f);
    }
    __syncthreads();
    if (tid == 0) {
        float acc = b4[0];
        for (int k = 0; k < 64; ++k) acc += f3[k] * W4[k];
        out[0] = acc;
    }
}

// ---------------------------------------------------------------------------
extern "C" void kernel_launch(void* const* d_in, const int* in_sizes, int n_in,
                              void* d_out, int out_size, void* d_ws, size_t ws_size,
                              hipStream_t stream)
{
    const float* g_mol   = (const float*)d_in[0];
    const float* feat_seq= (const float*)d_in[1];
    const float* smiles  = (const float*)d_in[2];
    const float* kmer    = (const float*)d_in[3];
    const float* edge_w  = (const float*)d_in[4];
    const float* w_ih0   = (const float*)d_in[5];
    const float* w_hh0   = (const float*)d_in[6];
    const float* b_ih0   = (const float*)d_in[7];
    const float* b_hh0   = (const float*)d_in[8];
    const float* w_ih1   = (const float*)d_in[9];
    const float* w_hh1   = (const float*)d_in[10];
    const float* b_ih1   = (const float*)d_in[11];
    const float* b_hh1   = (const float*)d_in[12];
    const float* Wq      = (const float*)d_in[13];
    const float* bq      = (const float*)d_in[14];
    const float* Wk      = (const float*)d_in[15];
    const float* bk      = (const float*)d_in[16];
    const float* Wv      = (const float*)d_in[17];
    const float* bv      = (const float*)d_in[18];
    const float* Wfc     = (const float*)d_in[19];
    const float* bfc     = (const float*)d_in[20];
    const float* W_gc1   = (const float*)d_in[21];
    const float* b_gc1   = (const float*)d_in[22];
    const float* W_gc2   = (const float*)d_in[23];
    const float* b_gc2   = (const float*)d_in[24];
    const float* W1      = (const float*)d_in[25];
    const float* b1      = (const float*)d_in[26];
    const float* W2      = (const float*)d_in[27];
    const float* b2      = (const float*)d_in[28];
    const float* W3      = (const float*)d_in[29];
    const float* b3      = (const float*)d_in[30];
    const float* W4      = (const float*)d_in[31];
    const float* b4      = (const float*)d_in[32];
    const int* esrc      = (const int*)d_in[33];
    const int* edst      = (const int*)d_in[34];

    float* ws    = (float*)d_ws;
    float* xgT   = ws + OFF_XGT;
    float* hT0   = ws + OFF_HT0;
    float* hT1   = ws + OFF_HT1;
    float* q     = ws + OFF_Q;
    float* k     = ws + OFF_K;
    float* v     = ws + OFF_V;
    float* arow  = ws + OFF_AROW;
    float* av    = ws + OFF_AV;
    float* feats = ws + OFF_FEATS;
    float* f1    = ws + OFF_F1;
    float* f2    = ws + OFF_F2;
    float* gsum  = ws + OFF_GSUM;
    float* outw  = ws + OFF_OUTW;
    int*   deg   = (int*)(ws + OFF_DEG);
    int*   rowp  = (int*)(ws + OFF_ROWP);
    int*   cur   = (int*)(ws + OFF_CUR);
    uint32_t* wpk = (uint32_t*)(ws + OFF_WPK);
    uint2* epack = (uint2*)(ws + OFF_EPACK);

    float* out_f = (float*)d_out;
    float* attn  = out_f + 1;   // [2048][2048] scores then softmax in place

    // zero gsum + outw + deg (contiguous)
    hipMemsetAsync(gsum, 0, (size_t)(128 + 50000 + 50000) * sizeof(float), stream);

    // weight prep + layer-0 input projection
    prep_kernel<<<512, 256, 0, stream>>>(w_hh0, w_hh1, wpk);
    xg0_kernel<<<256, 512, 0, stream>>>(g_mol, w_ih0, b_ih0, b_hh0, xgT);

    // layer-0 recurrence, edge histogram hidden under it
    lstm_fused_kernel<<<510, 512, 0, stream>>>(
        xgT, wpk, hT0, 0, esrc, edst, edge_w, deg, outw,
        rowp, epack, feat_seq, W_gc1, b_gc1, gsum);

    // CSR build
    scan_kernel<<<1, 1024, 0, stream>>>(deg, rowp, cur);
    fill_kernel<<<1172, 512, 0, stream>>>(esrc, edst, edge_w, cur, epack);

    // layer-1 input projection, then recurrence with GNN gather hidden under it
    xg1_kernel<<<256, 512, 0, stream>>>(hT0, w_ih1, b_ih1, b_hh1, xgT);
    lstm_fused_kernel<<<510, 512, 0, stream>>>(
        xgT, wpk + 65536, hT1, 1, esrc, edst, edge_w, deg, outw,
        rowp, epack, feat_seq, W_gc1, b_gc1, gsum);

    // attention
    qkv_kernel<<<128, 384, 0, stream>>>(hT1, Wq, bq, Wk, bk, Wv, bv, q, k, v);
    scores_kernel<<<dim3(128, 128), 256, 0, stream>>>(q, k, attn);
    softmax_kernel<<<2048, 256, 0, stream>>>(attn, arow);
    av_kernel<<<1, 128, 0, stream>>>(arow, v, av);
    gmolfc_kernel<<<1, 256, 0, stream>>>(av, Wfc, bfc, feats);
    feats_kernel<<<5, 256, 0, stream>>>(gsum, W_gc2, b_gc2, smiles, kmer, feats);

    // head
    mlp1_kernel<<<575, 256, 0, stream>>>(feats, W1, b1, f1);
    mlp2_kernel<<<256, 256, 0, stream>>>(f1, W2, b2, f2);
    mlp_tail_kernel<<<1, 256, 0, stream>>>(f2, W3, b3, W4, b4, out_f);
}

// Round 5
// 2570.185 us; speedup vs baseline: 2.0639x; 1.2845x over previous
//
#include <hip/hip_runtime.h>
#include <stdint.h>

// ---------------------------------------------------------------------------
// EMMPTNet: 2-layer bidir LSTM (T=2048,H=128) -> self-attn (attn matrix is
// output 1) -> 2-hop GCN (50k nodes, 600k edges) -> MLP (output 0).
// fp32 I/O. LSTM recurrence: quad-split (thread (q,s): k-chunk s of all 4
// gates of h_q), fp16 v_dot2 matvec, DPP quad-reduce/exchange (no pbuf),
// 1 barrier/step, double-buffered h in LDS. Grid=256 -> 1 block/CU so the
// two LSTM blocks own their CUs. GCN via CSR gather (no fp32 atomics).
// ---------------------------------------------------------------------------

#define T_SEQ 2048
#define NNODE 50000
#define NEDGE 600000

typedef _Float16 half2_t __attribute__((ext_vector_type(2)));

static __device__ __forceinline__ float fast_rcp(float x) {
#if __has_builtin(__builtin_amdgcn_rcpf)
    return __builtin_amdgcn_rcpf(x);
#else
    return 1.f / x;
#endif
}
static __device__ __forceinline__ float sigf(float x) { return fast_rcp(1.f + __expf(-x)); }
static __device__ __forceinline__ float tanh_fast(float x) { return 1.f - 2.f * fast_rcp(1.f + __expf(2.f * x)); }

static __device__ __forceinline__ float dot2h(float acc, uint32_t a, uint32_t b) {
#if __has_builtin(__builtin_amdgcn_fdot2)
    return __builtin_amdgcn_fdot2(__builtin_bit_cast(half2_t, a),
                                  __builtin_bit_cast(half2_t, b), acc, false);
#else
    half2_t ha = __builtin_bit_cast(half2_t, a);
    half2_t hb = __builtin_bit_cast(half2_t, b);
    return acc + (float)ha.x * (float)hb.x + (float)ha.y * (float)hb.y;
#endif
}

// quad_perm DPP: lane gets value of lane (quad-relative) PERM[s]
template<int CTRL>
static __device__ __forceinline__ float qperm(float x) {
    int r = __builtin_amdgcn_update_dpp(0, __builtin_bit_cast(int, x), CTRL, 0xF, 0xF, false);
    return __builtin_bit_cast(float, r);
}
// ctrl = v0 | v1<<2 | v2<<4 | v3<<6
#define QP_XOR1 0xB1   // [1,0,3,2]
#define QP_XOR2 0x4E   // [2,3,0,1]
#define QP_XOR3 0x1B   // [3,2,1,0]

// ---------------- workspace layout (4-byte word offsets) ----------------
constexpr size_t OFF_XGT   = 0;                      // [1024][2048] xg transposed
constexpr size_t OFF_HT0   = OFF_XGT + 2097152;      // [256][2048] h0 transposed
constexpr size_t OFF_HT1   = OFF_HT0 + 524288;       // [256][2048] h1 transposed
constexpr size_t OFF_Q     = OFF_HT1 + 524288;       // [2048][128]
constexpr size_t OFF_K     = OFF_Q + 262144;
constexpr size_t OFF_V     = OFF_K + 262144;
constexpr size_t OFF_AROW  = OFF_V + 262144;         // [2048]
constexpr size_t OFF_AV    = OFF_AROW + 2048;        // [128]
constexpr size_t OFF_FEATS = OFF_AV + 128;           // [1152]
constexpr size_t OFF_F1    = OFF_FEATS + 1152;       // [576]
constexpr size_t OFF_F2    = OFF_F1 + 576;           // [256]
constexpr size_t OFF_GSUM  = OFF_F2 + 256;           // [128]   (memset group start)
constexpr size_t OFF_OUTW  = OFF_GSUM + 128;         // [50000] fp32
constexpr size_t OFF_DEG   = OFF_OUTW + 50000;       // [50000] int (memset group end)
constexpr size_t OFF_ROWP  = OFF_DEG + 50000;        // [50000] int
constexpr size_t OFF_CUR   = OFF_ROWP + 50000;       // [50000] int
constexpr size_t OFF_WPK   = OFF_CUR + 50000;        // [131072] u32 packed fp16 w_hh
constexpr size_t OFF_EPACK = OFF_WPK + 131072;       // [600000] uint2
constexpr size_t WS_WORDS  = OFF_EPACK + 1200000;

// ---------------- one-time prep: pack w_hh (both layers) to fp16 pairs.
// wpk index (within layer) = ((dir*128+q)*4 + s)*64 + m*16 + kk
//   = dir<<15 | q<<8 | s<<6 | m<<4 | kk
// value = half2( w[dir][m*128+q][32s+2kk], w[dir][m*128+q][32s+2kk+1] )
__global__ __launch_bounds__(256) void prep_kernel(
    const float* __restrict__ w_hh0, const float* __restrict__ w_hh1,
    uint32_t* __restrict__ wpk)
{
    int i = blockIdx.x * 256 + threadIdx.x;
    if (i >= 131072) return;
    int layer = i >> 16;
    int r = i & 65535;
    int kk = r & 15, m = (r >> 4) & 3, sidx = (r >> 6) & 3, q = (r >> 8) & 127, dirv = (r >> 15) & 1;
    const float* w = layer ? w_hh1 : w_hh0;
    const float* row = w + ((size_t)dirv * 512 + m * 128 + q) * 128;
    int k0 = 32 * sidx + 2 * kk;
    half2_t hv;
    hv.x = (_Float16)row[k0];
    hv.y = (_Float16)row[k0 + 1];
    wpk[i] = __builtin_bit_cast(uint32_t, hv);
}

// ---------------- layer-0 input projection -> xgT[row][t] (biases folded)
__global__ __launch_bounds__(512) void xg0_kernel(
    const float* __restrict__ g_mol, const float* __restrict__ w_ih,
    const float* __restrict__ b_ih, const float* __restrict__ b_hh,
    float* __restrict__ xgT)
{
    int b = blockIdx.x;
    int dir = b >> 7, t0 = (b & 127) * 16;
    int r = threadIdx.x;
    __shared__ float xs[272];
    if (r < 272) xs[r] = g_mol[t0 * 17 + r];
    __syncthreads();
    const float* wrow = w_ih + (size_t)(dir * 512 + r) * 17;
    float wv[17];
#pragma unroll
    for (int k = 0; k < 17; ++k) wv[k] = wrow[k];
    float bias = b_ih[dir * 512 + r] + b_hh[dir * 512 + r];
    float acc[16];
#pragma unroll
    for (int tt = 0; tt < 16; ++tt) {
        float a = bias;
#pragma unroll
        for (int k = 0; k < 17; ++k) a += xs[tt * 17 + k] * wv[k];
        acc[tt] = a;
    }
    float* orow = xgT + (size_t)(dir * 512 + r) * 2048 + t0;
    *(float4*)(orow + 0)  = make_float4(acc[0], acc[1], acc[2], acc[3]);
    *(float4*)(orow + 4)  = make_float4(acc[4], acc[5], acc[6], acc[7]);
    *(float4*)(orow + 8)  = make_float4(acc[8], acc[9], acc[10], acc[11]);
    *(float4*)(orow + 12) = make_float4(acc[12], acc[13], acc[14], acc[15]);
}

// ---------------- layer-1 input projection: hT0 -> xgT[row][t]
__global__ __launch_bounds__(512) void xg1_kernel(
    const float* __restrict__ hT0, const float* __restrict__ w_ih,
    const float* __restrict__ b_ih, const float* __restrict__ b_hh,
    float* __restrict__ xgT)
{
    int b = blockIdx.x;
    int dir = b >> 7, t0 = (b & 127) * 16;
    int tid = threadIdx.x;
    __shared__ float xs[16 * 256];            // [tt][k]
    for (int u = tid; u < 1024; u += 512) {
        int k = u >> 2, j4 = u & 3;
        float4 v = *(const float4*)(hT0 + (size_t)k * 2048 + t0 + 4 * j4);
        xs[(4 * j4 + 0) * 256 + k] = v.x;
        xs[(4 * j4 + 1) * 256 + k] = v.y;
        xs[(4 * j4 + 2) * 256 + k] = v.z;
        xs[(4 * j4 + 3) * 256 + k] = v.w;
    }
    __syncthreads();
    int r = tid;
    float bias = b_ih[dir * 512 + r] + b_hh[dir * 512 + r];
    float acc[16];
#pragma unroll
    for (int tt = 0; tt < 16; ++tt) acc[tt] = bias;
    const float4* w4 = reinterpret_cast<const float4*>(w_ih + (size_t)(dir * 512 + r) * 256);
    const float4* xs4 = reinterpret_cast<const float4*>(xs);
    for (int k4 = 0; k4 < 64; ++k4) {
        float4 w = w4[k4];
#pragma unroll
        for (int tt = 0; tt < 16; ++tt) {
            float4 x = xs4[tt * 64 + k4];
            acc[tt] += x.x * w.x + x.y * w.y + x.z * w.z + x.w * w.w;
        }
    }
    float* orow = xgT + (size_t)(dir * 512 + r) * 2048 + t0;
    *(float4*)(orow + 0)  = make_float4(acc[0], acc[1], acc[2], acc[3]);
    *(float4*)(orow + 4)  = make_float4(acc[4], acc[5], acc[6], acc[7]);
    *(float4*)(orow + 8)  = make_float4(acc[8], acc[9], acc[10], acc[11]);
    *(float4*)(orow + 12) = make_float4(acc[12], acc[13], acc[14], acc[15]);
}

// ---------------- fused: blocks 0,1 = LSTM recurrence (one per direction);
// blocks 2..255 = side work (mode 0: edge hist + outw; mode 1: CSR gather).
// Grid MUST be 256 so each block gets a CU to itself.
__global__ __launch_bounds__(512) void lstm_fused_kernel(
    const float* __restrict__ xgT, const uint32_t* __restrict__ wpk,
    float* __restrict__ hT, int mode,
    const int* __restrict__ esrc, const int* __restrict__ edst,
    const float* __restrict__ ew,
    int* __restrict__ deg, float* __restrict__ outw,
    const int* __restrict__ rowp, const uint2* __restrict__ epack,
    const float* __restrict__ feat_seq,
    const float* __restrict__ Wgc1, const float* __restrict__ bgc1,
    float* __restrict__ gsum)
{
    __shared__ __align__(16) float smem[17664];
    const int tid = threadIdx.x;

    if (blockIdx.x >= 2) {
        if (mode == 0) {
            int stride = (gridDim.x - 2) * 512;
            for (int e = (blockIdx.x - 2) * 512 + tid; e < NEDGE; e += stride) {
                atomicAdd(&deg[edst[e]], 1);
                atomicAdd(&outw[esrc[e]], ew[e]);
            }
        } else {
            // CSR gather: agg1 row -> relu(agg1@W+b) -> gsum += outw[n]*h1
            float* wt   = smem;            // 16384 = W_gc1 [k][o]
            float* bg   = smem + 16384;    // 128
            float* aggl = smem + 16512;    // 8 waves x 128
            float* gbuf = smem + 17536;    // 128
            {
                float4* d4 = (float4*)wt;
                const float4* s4 = (const float4*)Wgc1;
                for (int u = tid; u < 4096; u += 512) d4[u] = s4[u];
                if (tid < 128) { bg[tid] = bgc1[tid]; gbuf[tid] = 0.f; }
            }
            __syncthreads();
            int wv = tid >> 6, lane = tid & 63;
            float ga0 = 0.f, ga1 = 0.f;
            int nwaves = (gridDim.x - 2) * 8;
            for (int n = (blockIdx.x - 2) * 8 + wv; n < NNODE; n += nwaves) {
                int st = rowp[n];
                int dg = deg[n];
                float a0 = 0.f, a1 = 0.f;
                for (int i = 0; i < dg; ++i) {
                    uint2 ep = epack[st + i];
                    float w = __uint_as_float(ep.y);
                    float2 f = *(const float2*)(feat_seq + (size_t)ep.x * 128 + 2 * lane);
                    a0 += w * f.x;
                    a1 += w * f.y;
                }
                *(float2*)&aggl[wv * 128 + 2 * lane] = make_float2(a0, a1);
                float h0 = bg[2 * lane], h1v = bg[2 * lane + 1];
                for (int k = 0; k < 128; ++k) {
                    float av_ = aggl[wv * 128 + k];
                    float2 wv2 = *(const float2*)&wt[k * 128 + 2 * lane];
                    h0 += av_ * wv2.x;
                    h1v += av_ * wv2.y;
                }
                float ow = outw[n];
                ga0 += ow * fmaxf(h0, 0.f);
                ga1 += ow * fmaxf(h1v, 0.f);
            }
            atomicAdd(&gbuf[2 * lane], ga0);
            atomicAdd(&gbuf[2 * lane + 1], ga1);
            __syncthreads();
            if (tid < 128) atomicAdd(&gsum[tid], gbuf[tid]);
        }
        return;
    }

    // ------------- LSTM recurrence: quad-split DPP, 1 barrier/step -------------
#if __has_builtin(__builtin_amdgcn_s_setprio)
    __builtin_amdgcn_s_setprio(3);
#endif
    const int dir = blockIdx.x;
    const int q = tid >> 2;     // h index 0..127
    const int s = tid & 3;      // k-chunk / finalized gate

    _Float16* hbuf = reinterpret_cast<_Float16*>(smem);   // [2][128]

    // 64 packed-u32 weights: 4 gates x 16 pairs (k in [32s,32s+32))
    const uint4* wt4 = reinterpret_cast<const uint4*>(
        wpk + (((size_t)(dir * 128 + q) * 4 + s) * 64));
    uint32_t wr[4][16];
#pragma unroll
    for (int m = 0; m < 4; ++m)
#pragma unroll
        for (int j = 0; j < 4; ++j) {
            uint4 wv = wt4[m * 4 + j];
            wr[m][4 * j + 0] = wv.x; wr[m][4 * j + 1] = wv.y;
            wr[m][4 * j + 2] = wv.z; wr[m][4 * j + 3] = wv.w;
        }

    // branchless-activation constants (s==2 -> tanh, else sigmoid)
    const float ascale = (s == 2) ? 2.f : -1.f;
    const float oscale = (s == 2) ? -2.f : 1.f;
    const float obias  = (s == 2) ? 1.f : 0.f;

    if (tid < 128) reinterpret_cast<uint32_t*>(hbuf)[tid] = 0u;  // both buffers
    float c = 0.f;
    float hq[16];
    __syncthreads();

    const float* xrow = xgT + (size_t)(dir * 512 + (s * 128 + q)) * 2048;
    float* hrow = hT + (size_t)(dir * 128 + q) * 2048;

    const int base0 = dir ? 2032 : 0;
    float4 nA = *(const float4*)(xrow + base0);
    float4 nB = *(const float4*)(xrow + base0 + 4);
    float4 nC = *(const float4*)(xrow + base0 + 8);
    float4 nD = *(const float4*)(xrow + base0 + 12);

    for (int s16 = 0; s16 < 128; ++s16) {
        const int base = dir ? (2032 - s16 * 16) : (s16 * 16);
        float4 A = nA, B4 = nB, C4 = nC, D4 = nD;
        if (s16 < 127) {
            const int nb = dir ? (base - 16) : (base + 16);
            nA = *(const float4*)(xrow + nb);
            nB = *(const float4*)(xrow + nb + 4);
            nC = *(const float4*)(xrow + nb + 8);
            nD = *(const float4*)(xrow + nb + 12);
        }
        float xq[16];
        if (dir) {
            xq[0]=D4.w;  xq[1]=D4.z;  xq[2]=D4.y;  xq[3]=D4.x;
            xq[4]=C4.w;  xq[5]=C4.z;  xq[6]=C4.y;  xq[7]=C4.x;
            xq[8]=B4.w;  xq[9]=B4.z;  xq[10]=B4.y; xq[11]=B4.x;
            xq[12]=A.w;  xq[13]=A.z;  xq[14]=A.y;  xq[15]=A.x;
        } else {
            xq[0]=A.x;   xq[1]=A.y;   xq[2]=A.z;   xq[3]=A.w;
            xq[4]=B4.x;  xq[5]=B4.y;  xq[6]=B4.z;  xq[7]=B4.w;
            xq[8]=C4.x;  xq[9]=C4.y;  xq[10]=C4.z; xq[11]=C4.w;
            xq[12]=D4.x; xq[13]=D4.y; xq[14]=D4.z; xq[15]=D4.w;
        }
#pragma unroll
        for (int i = 0; i < 16; ++i) {
            const int p = i & 1;
            const uint4* h4 = reinterpret_cast<const uint4*>(hbuf + p * 128 + s * 32);
            float a0 = 0.f, a1 = 0.f, a2 = 0.f, a3 = 0.f;
#pragma unroll
            for (int j = 0; j < 4; ++j) {
                uint4 hv = h4[j];
                a0 = dot2h(a0, hv.x, wr[0][4 * j + 0]);
                a0 = dot2h(a0, hv.y, wr[0][4 * j + 1]);
                a0 = dot2h(a0, hv.z, wr[0][4 * j + 2]);
                a0 = dot2h(a0, hv.w, wr[0][4 * j + 3]);
                a1 = dot2h(a1, hv.x, wr[1][4 * j + 0]);
                a1 = dot2h(a1, hv.y, wr[1][4 * j + 1]);
                a1 = dot2h(a1, hv.z, wr[1][4 * j + 2]);
                a1 = dot2h(a1, hv.w, wr[1][4 * j + 3]);
                a2 = dot2h(a2, hv.x, wr[2][4 * j + 0]);
                a2 = dot2h(a2, hv.y, wr[2][4 * j + 1]);
                a2 = dot2h(a2, hv.z, wr[2][4 * j + 2]);
                a2 = dot2h(a2, hv.w, wr[2][4 * j + 3]);
                a3 = dot2h(a3, hv.x, wr[3][4 * j + 0]);
                a3 = dot2h(a3, hv.y, wr[3][4 * j + 1]);
                a3 = dot2h(a3, hv.z, wr[3][4 * j + 2]);
                a3 = dot2h(a3, hv.w, wr[3][4 * j + 3]);
            }
            // quad butterfly reduce (DPP, VALU pipe)
            a0 += qperm<QP_XOR1>(a0); a0 += qperm<QP_XOR2>(a0);
            a1 += qperm<QP_XOR1>(a1); a1 += qperm<QP_XOR2>(a1);
            a2 += qperm<QP_XOR1>(a2); a2 += qperm<QP_XOR2>(a2);
            a3 += qperm<QP_XOR1>(a3); a3 += qperm<QP_XOR2>(a3);
            // pick own gate (s), add xg, activate
            float g01 = (s & 1) ? a1 : a0;
            float g23 = (s & 1) ? a3 : a2;
            float gp = ((s & 2) ? g23 : g01) + xq[i];
            float e = __expf(gp * ascale);
            float r = fast_rcp(1.f + e);
            float av_ = fmaf(r, oscale, obias);     // lane s holds gate s of h_q
            // gather the quad's gates (valid at lane s==0: own=i,b1=f,b2=g,b3=o)
            float b1 = qperm<QP_XOR1>(av_);
            float b2 = qperm<QP_XOR2>(av_);
            float b3 = qperm<QP_XOR3>(av_);
            c = fmaf(b1, c, av_ * b2);              // c' = f*c + i*g  (lane 0)
            float e2 = __expf(2.f * c);
            float r2 = fast_rcp(1.f + e2);
            float hv = b3 * (1.f - 2.f * r2);       // o * tanh(c')    (lane 0)
            if (s == 0) {
                hbuf[(p ^ 1) * 128 + q] = (_Float16)hv;
                hq[dir ? (15 - i) : i] = hv;
            }
            __syncthreads();
        }
        if (s == 0) {
            *(float4*)(hrow + base + 0)  = make_float4(hq[0], hq[1], hq[2], hq[3]);
            *(float4*)(hrow + base + 4)  = make_float4(hq[4], hq[5], hq[6], hq[7]);
            *(float4*)(hrow + base + 8)  = make_float4(hq[8], hq[9], hq[10], hq[11]);
            *(float4*)(hrow + base + 12) = make_float4(hq[12], hq[13], hq[14], hq[15]);
        }
    }
}

// ---------------- CSR scan: deg -> rowp (exclusive), cursor copy
__global__ __launch_bounds__(1024) void scan_kernel(
    const int* __restrict__ deg, int* __restrict__ rowp, int* __restrict__ cur)
{
    __shared__ int part[1024];
    int t = threadIdx.x;
    int lo = t * 49, hi = min(lo + 49, NNODE);
    int s = 0;
    for (int i = lo; i < hi; ++i) s += deg[i];
    part[t] = s;
    __syncthreads();
    for (int off = 1; off < 1024; off <<= 1) {
        int v = (t >= off) ? part[t - off] : 0;
        __syncthreads();
        part[t] += v;
        __syncthreads();
    }
    int run = t ? part[t - 1] : 0;
    for (int i = lo; i < hi; ++i) {
        rowp[i] = run;
        cur[i] = run;
        run += deg[i];
    }
}

// ---------------- CSR fill: epack[pos] = {src, weight}
__global__ __launch_bounds__(512) void fill_kernel(
    const int* __restrict__ esrc, const int* __restrict__ edst,
    const float* __restrict__ ew, int* __restrict__ cur,
    uint2* __restrict__ epack)
{
    int e = blockIdx.x * 512 + threadIdx.x;
    if (e >= NEDGE) return;
    int d = edst[e];
    int pos = atomicAdd(&cur[d], 1);
    epack[pos] = make_uint2((unsigned)esrc[e], __float_as_uint(ew[e]));
}

// ---------------- q/k/v projection from hT1, 16 timesteps per block
__global__ __launch_bounds__(384) void qkv_kernel(
    const float* __restrict__ hT1,
    const float* __restrict__ Wq, const float* __restrict__ bq,
    const float* __restrict__ Wk, const float* __restrict__ bk,
    const float* __restrict__ Wv, const float* __restrict__ bv,
    float* __restrict__ q, float* __restrict__ k, float* __restrict__ v)
{
    int t0 = blockIdx.x * 16, tid = threadIdx.x;
    __shared__ float xs[16 * 256];
    for (int u = tid; u < 1024; u += 384) {
        int kk = u >> 2, j4 = u & 3;
        float4 vv = *(const float4*)(hT1 + (size_t)kk * 2048 + t0 + 4 * j4);
        xs[(4 * j4 + 0) * 256 + kk] = vv.x;
        xs[(4 * j4 + 1) * 256 + kk] = vv.y;
        xs[(4 * j4 + 2) * 256 + kk] = vv.z;
        xs[(4 * j4 + 3) * 256 + kk] = vv.w;
    }
    __syncthreads();
    int which = tid >> 7, j = tid & 127;
    const float* W = (which == 0) ? Wq : (which == 1) ? Wk : Wv;
    const float* B = (which == 0) ? bq : (which == 1) ? bk : bv;
    float* out = (which == 0) ? q : (which == 1) ? k : v;
    float bias = B[j];
    float acc[16];
#pragma unroll
    for (int tt = 0; tt < 16; ++tt) acc[tt] = bias;
    const float4* w4 = reinterpret_cast<const float4*>(W + (size_t)j * 256);
    const float4* xs4 = reinterpret_cast<const float4*>(xs);
    for (int k4 = 0; k4 < 64; ++k4) {
        float4 w = w4[k4];
#pragma unroll
        for (int tt = 0; tt < 16; ++tt) {
            float4 x = xs4[tt * 64 + k4];
            acc[tt] += x.x * w.x + x.y * w.y + x.z * w.z + x.w * w.w;
        }
    }
#pragma unroll
    for (int tt = 0; tt < 16; ++tt) out[(size_t)(t0 + tt) * 128 + j] = acc[tt];
}

// ---------------- scores = q @ k.T / sqrt(128), straight into d_out+1
__global__ __launch_bounds__(256) void scores_kernel(
    const float* __restrict__ q, const float* __restrict__ kmat, float* __restrict__ attn)
{
    int bi = blockIdx.y, bj = blockIdx.x, tid = threadIdx.x;
    __shared__ float qs[16][132];
    __shared__ float ks[16][132];
    for (int u = tid; u < 2048; u += 256) {
        int rr = u >> 7, cc = u & 127;
        qs[rr][cc] = q[(size_t)(bi * 16 + rr) * 128 + cc];
        ks[rr][cc] = kmat[(size_t)(bj * 16 + rr) * 128 + cc];
    }
    __syncthreads();
    int ty = tid >> 4, tx = tid & 15;
    const float4* qrow = reinterpret_cast<const float4*>(&qs[ty][0]);
    const float4* krow = reinterpret_cast<const float4*>(&ks[tx][0]);
    float acc = 0.f;
#pragma unroll
    for (int c4 = 0; c4 < 32; ++c4) {
        float4 a = qrow[c4], b = krow[c4];
        acc += a.x * b.x + a.y * b.y + a.z * b.z + a.w * b.w;
    }
    attn[(size_t)(bi * 16 + ty) * 2048 + (bj * 16 + tx)] = acc * 0.08838834764831845f;
}

// ---------------- softmax per row, in place; saves row 2047
__global__ __launch_bounds__(256) void softmax_kernel(
    float* __restrict__ attn, float* __restrict__ attnrow)
{
    int i = blockIdx.x, tid = threadIdx.x;
    float* row = attn + (size_t)i * 2048;
    __shared__ float red[256];
    float m = -1e30f;
    for (int j = tid; j < 2048; j += 256) m = fmaxf(m, row[j]);
    red[tid] = m; __syncthreads();
    for (int s = 128; s > 0; s >>= 1) { if (tid < s) red[tid] = fmaxf(red[tid], red[tid + s]); __syncthreads(); }
    m = red[0]; __syncthreads();
    float sum = 0.f;
    for (int j = tid; j < 2048; j += 256) sum += __expf(row[j] - m);
    red[tid] = sum; __syncthreads();
    for (int s = 128; s > 0; s >>= 1) { if (tid < s) red[tid] += red[tid + s]; __syncthreads(); }
    float inv = 1.f / red[0];
    for (int j = tid; j < 2048; j += 256) {
        float w = __expf(row[j] - m) * inv;
        row[j] = w;
        if (i == 2047) attnrow[j] = w;
    }
}

// ---------------- av[j] = sum_t attnrow[t] * v[t][j]
__global__ __launch_bounds__(128) void av_kernel(
    const float* __restrict__ attnrow, const float* __restrict__ v, float* __restrict__ av)
{
    int j = threadIdx.x;
    float acc = 0.f;
#pragma unroll 8
    for (int t = 0; t < 2048; ++t) acc += attnrow[t] * v[(size_t)t * 128 + j];
    av[j] = acc;
}

// ---------------- gmol = av @ Wfc.T + bfc -> feats[256..511]
__global__ __launch_bounds__(256) void gmolfc_kernel(
    const float* __restrict__ av, const float* __restrict__ Wfc, const float* __restrict__ bfc,
    float* __restrict__ feats)
{
    int o = threadIdx.x;
    __shared__ float a[128];
    if (o < 128) a[o] = av[o];
    __syncthreads();
    const float4* w4 = reinterpret_cast<const float4*>(Wfc + (size_t)o * 128);
    const float4* a4 = reinterpret_cast<const float4*>(a);
    float acc = bfc[o];
#pragma unroll 8
    for (int kk = 0; kk < 32; ++kk) {
        float4 w = w4[kk], x = a4[kk];
        acc += x.x * w.x + x.y * w.y + x.z * w.z + x.w * w.w;
    }
    feats[256 + o] = acc;
}

// ---------------- feats: hg (=(gsum/N)@W_gc2+b_gc2) + smiles + kmer
__global__ __launch_bounds__(256) void feats_kernel(
    const float* __restrict__ gsum, const float* __restrict__ W_gc2, const float* __restrict__ b_gc2,
    const float* __restrict__ smiles, const float* __restrict__ kmer, float* __restrict__ feats)
{
    int i = blockIdx.x * 256 + threadIdx.x;
    if (i < 256) {
        float dotv = 0.f;
#pragma unroll 4
        for (int k = 0; k < 128; ++k) dotv += gsum[k] * W_gc2[(size_t)k * 256 + i];
        feats[i] = b_gc2[i] + dotv * (1.f / (float)NNODE);
    } else if (i >= 512 && i < 1086) {
        feats[i] = smiles[i - 512];
    } else if (i >= 1086 && i < 1150) {
        feats[i] = kmer[i - 1086];
    }
}

// ---------------- MLP layers
__global__ __launch_bounds__(256) void mlp1_kernel(
    const float* __restrict__ feats, const float* __restrict__ W1, const float* __restrict__ b1,
    float* __restrict__ f1)
{
    int o = blockIdx.x, tid = threadIdx.x;
    const float* w = W1 + (size_t)o * 1150;
    float acc = 0.f;
    for (int k = tid; k < 1150; k += 256) acc += feats[k] * w[k];
    __shared__ float red[256];
    red[tid] = acc; __syncthreads();
    for (int s = 128; s > 0; s >>= 1) { if (tid < s) red[tid] += red[tid + s]; __syncthreads(); }
    if (tid == 0) f1[o] = fmaxf(red[0] + b1[o], 0.f);
}

__global__ __launch_bounds__(256) void mlp2_kernel(
    const float* __restrict__ f1, const float* __restrict__ W2, const float* __restrict__ b2,
    float* __restrict__ f2)
{
    int o = blockIdx.x, tid = threadIdx.x;
    const float* w = W2 + (size_t)o * 575;
    float acc = 0.f;
    for (int k = tid; k < 575; k += 256) acc += f1[k] * w[k];
    __shared__ float red[256];
    red[tid] = acc; __syncthreads();
    for (int s = 128; s > 0; s >>= 1) { if (tid < s) red[tid] += red[tid + s]; __syncthreads(); }
    if (tid == 0) f2[o] = fmaxf(red[0] + b2[o], 0.f);
}

__global__ __launch_bounds__(256) void mlp_tail_kernel(
    const float* __restrict__ f2,
    const float* __restrict__ W3, const float* __restrict__ b3,
    const float* __restrict__ W4, const float* __restrict__ b4,
    float* __restrict__ out)
{
    __shared__ float f2s[256];
    __shared__ float f3[64];
    int tid = threadIdx.x;
    f2s[tid] = f2[tid];
    __syncthreads();
    if (tid < 64) {
        const float* w = W3 + (size_t)tid * 256;
        float acc = b3[tid];
        for (int k = 0; k < 256; ++k) acc += f2s[k] * w[k];
        f3[tid] = fmaxf(acc, 0.f);
    }
    __syncthreads();
    if (tid == 0) {
        float acc = b4[0];
        for (int k = 0; k < 64; ++k) acc += f3[k] * W4[k];
        out[0] = acc;
    }
}

// ---------------------------------------------------------------------------
extern "C" void kernel_launch(void* const* d_in, const int* in_sizes, int n_in,
                              void* d_out, int out_size, void* d_ws, size_t ws_size,
                              hipStream_t stream)
{
    const float* g_mol   = (const float*)d_in[0];
    const float* feat_seq= (const float*)d_in[1];
    const float* smiles  = (const float*)d_in[2];
    const float* kmer    = (const float*)d_in[3];
    const float* edge_w  = (const float*)d_in[4];
    const float* w_ih0   = (const float*)d_in[5];
    const float* w_hh0   = (const float*)d_in[6];
    const float* b_ih0   = (const float*)d_in[7];
    const float* b_hh0   = (const float*)d_in[8];
    const float* w_ih1   = (const float*)d_in[9];
    const float* w_hh1   = (const float*)d_in[10];
    const float* b_ih1   = (const float*)d_in[11];
    const float* b_hh1   = (const float*)d_in[12];
    const float* Wq      = (const float*)d_in[13];
    const float* bq      = (const float*)d_in[14];
    const float* Wk      = (const float*)d_in[15];
    const float* bk      = (const float*)d_in[16];
    const float* Wv      = (const float*)d_in[17];
    const float* bv      = (const float*)d_in[18];
    const float* Wfc     = (const float*)d_in[19];
    const float* bfc     = (const float*)d_in[20];
    const float* W_gc1   = (const float*)d_in[21];
    const float* b_gc1   = (const float*)d_in[22];
    const float* W_gc2   = (const float*)d_in[23];
    const float* b_gc2   = (const float*)d_in[24];
    const float* W1      = (const float*)d_in[25];
    const float* b1      = (const float*)d_in[26];
    const float* W2      = (const float*)d_in[27];
    const float* b2      = (const float*)d_in[28];
    const float* W3      = (const float*)d_in[29];
    const float* b3      = (const float*)d_in[30];
    const float* W4      = (const float*)d_in[31];
    const float* b4      = (const float*)d_in[32];
    const int* esrc      = (const int*)d_in[33];
    const int* edst      = (const int*)d_in[34];

    float* ws    = (float*)d_ws;
    float* xgT   = ws + OFF_XGT;
    float* hT0   = ws + OFF_HT0;
    float* hT1   = ws + OFF_HT1;
    float* q     = ws + OFF_Q;
    float* k     = ws + OFF_K;
    float* v     = ws + OFF_V;
    float* arow  = ws + OFF_AROW;
    float* av    = ws + OFF_AV;
    float* feats = ws + OFF_FEATS;
    float* f1    = ws + OFF_F1;
    float* f2    = ws + OFF_F2;
    float* gsum  = ws + OFF_GSUM;
    float* outw  = ws + OFF_OUTW;
    int*   deg   = (int*)(ws + OFF_DEG);
    int*   rowp  = (int*)(ws + OFF_ROWP);
    int*   cur   = (int*)(ws + OFF_CUR);
    uint32_t* wpk = (uint32_t*)(ws + OFF_WPK);
    uint2* epack = (uint2*)(ws + OFF_EPACK);

    float* out_f = (float*)d_out;
    float* attn  = out_f + 1;   // [2048][2048] scores then softmax in place

    // zero gsum + outw + deg (contiguous)
    hipMemsetAsync(gsum, 0, (size_t)(128 + 50000 + 50000) * sizeof(float), stream);

    // weight prep + layer-0 input projection
    prep_kernel<<<512, 256, 0, stream>>>(w_hh0, w_hh1, wpk);
    xg0_kernel<<<256, 512, 0, stream>>>(g_mol, w_ih0, b_ih0, b_hh0, xgT);

    // layer-0 recurrence, edge histogram hidden under it (grid=256: 1 block/CU)
    lstm_fused_kernel<<<256, 512, 0, stream>>>(
        xgT, wpk, hT0, 0, esrc, edst, edge_w, deg, outw,
        rowp, epack, feat_seq, W_gc1, b_gc1, gsum);

    // CSR build
    scan_kernel<<<1, 1024, 0, stream>>>(deg, rowp, cur);
    fill_kernel<<<1172, 512, 0, stream>>>(esrc, edst, edge_w, cur, epack);

    // layer-1 input projection, then recurrence with GNN gather hidden under it
    xg1_kernel<<<256, 512, 0, stream>>>(hT0, w_ih1, b_ih1, b_hh1, xgT);
    lstm_fused_kernel<<<256, 512, 0, stream>>>(
        xgT, wpk + 65536, hT1, 1, esrc, edst, edge_w, deg, outw,
        rowp, epack, feat_seq, W_gc1, b_gc1, gsum);

    // attention
    qkv_kernel<<<128, 384, 0, stream>>>(hT1, Wq, bq, Wk, bk, Wv, bv, q, k, v);
    scores_kernel<<<dim3(128, 128), 256, 0, stream>>>(q, k, attn);
    softmax_kernel<<<2048, 256, 0, stream>>>(attn, arow);
    av_kernel<<<1, 128, 0, stream>>>(arow, v, av);
    gmolfc_kernel<<<1, 256, 0, stream>>>(av, Wfc, bfc, feats);
    feats_kernel<<<5, 256, 0, stream>>>(gsum, W_gc2, b_gc2, smiles, kmer, feats);

    // head
    mlp1_kernel<<<575, 256, 0, stream>>>(feats, W1, b1, f1);
    mlp2_kernel<<<256, 256, 0, stream>>>(f1, W2, b2, f2);
    mlp_tail_kernel<<<1, 256, 0, stream>>>(f2, W3, b3, W4, b4, out_f);
}

// Round 6
// 2530.524 us; speedup vs baseline: 2.0963x; 1.0157x over previous
//
#include <hip/hip_runtime.h>
#include <stdint.h>

// ---------------------------------------------------------------------------
// EMMPTNet: 2-layer bidir LSTM (T=2048,H=128) -> self-attn (attn matrix is
// output 1) -> 2-hop GCN (50k nodes, 600k edges) -> MLP (output 0).
// fp32 I/O. LSTM recurrence: quad-split (thread (q,s): k-chunk s of all 4
// gates of h_q), fp16 v_dot2 matvec with exp2-baked gate scales, DPP
// quad-reduce/exchange, 1 barrier/step, double-buffered h in LDS.
// amdgpu_waves_per_eu(2,2): 256-VGPR budget so weights stay in arch VGPRs
// (round-5 VGPR_Count=72 proved AGPR spill => 2x issue). 84KB LDS => 1
// block/CU guaranteed. GCN via CSR gather (no fp32 atomics).
// ---------------------------------------------------------------------------

#define T_SEQ 2048
#define NNODE 50000
#define NEDGE 600000

typedef _Float16 half2_t __attribute__((ext_vector_type(2)));

static __device__ __forceinline__ float fast_rcp(float x) {
#if __has_builtin(__builtin_amdgcn_rcpf)
    return __builtin_amdgcn_rcpf(x);
#else
    return 1.f / x;
#endif
}
static __device__ __forceinline__ float exp2_fast(float x) {
#if __has_builtin(__builtin_amdgcn_exp2f)
    return __builtin_amdgcn_exp2f(x);
#else
    return exp2f(x);
#endif
}

static __device__ __forceinline__ float dot2h(float acc, uint32_t a, uint32_t b) {
#if __has_builtin(__builtin_amdgcn_fdot2)
    return __builtin_amdgcn_fdot2(__builtin_bit_cast(half2_t, a),
                                  __builtin_bit_cast(half2_t, b), acc, false);
#else
    half2_t ha = __builtin_bit_cast(half2_t, a);
    half2_t hb = __builtin_bit_cast(half2_t, b);
    return acc + (float)ha.x * (float)hb.x + (float)ha.y * (float)hb.y;
#endif
}

// quad_perm DPP: lane gets value of lane (quad-relative) PERM[s]
template<int CTRL>
static __device__ __forceinline__ float qperm(float x) {
    int r = __builtin_amdgcn_update_dpp(0, __builtin_bit_cast(int, x), CTRL, 0xF, 0xF, false);
    return __builtin_bit_cast(float, r);
}
#define QP_XOR1 0xB1   // [1,0,3,2]
#define QP_XOR2 0x4E   // [2,3,0,1]
#define QP_XOR3 0x1B   // [3,2,1,0]

// gate pre-scales for exp2-based activations:
// sigmoid(x) = rcp(1 + 2^(-1.4427 x));  tanh(x) = 1 - 2 rcp(1 + 2^(2.8854 x))
#define SIG_SCALE  (-1.44269504f)
#define TANH_SCALE ( 2.88539008f)

// ---------------- workspace layout (4-byte word offsets) ----------------
constexpr size_t OFF_XGT   = 0;                      // [1024][2048] xg transposed (pre-scaled)
constexpr size_t OFF_HT0   = OFF_XGT + 2097152;      // [256][2048] h0 transposed
constexpr size_t OFF_HT1   = OFF_HT0 + 524288;       // [256][2048] h1 transposed
constexpr size_t OFF_Q     = OFF_HT1 + 524288;       // [2048][128]
constexpr size_t OFF_K     = OFF_Q + 262144;
constexpr size_t OFF_V     = OFF_K + 262144;
constexpr size_t OFF_AROW  = OFF_V + 262144;         // [2048]
constexpr size_t OFF_AV    = OFF_AROW + 2048;        // [128]
constexpr size_t OFF_FEATS = OFF_AV + 128;           // [1152]
constexpr size_t OFF_F1    = OFF_FEATS + 1152;       // [576]
constexpr size_t OFF_F2    = OFF_F1 + 576;           // [256]
constexpr size_t OFF_GSUM  = OFF_F2 + 256;           // [128]   (memset group start)
constexpr size_t OFF_OUTW  = OFF_GSUM + 128;         // [50000] fp32
constexpr size_t OFF_DEG   = OFF_OUTW + 50000;       // [50000] int (memset group end)
constexpr size_t OFF_ROWP  = OFF_DEG + 50000;        // [50000] int
constexpr size_t OFF_CUR   = OFF_ROWP + 50000;       // [50000] int
constexpr size_t OFF_WPK   = OFF_CUR + 50000;        // [131072] u32 packed fp16 w_hh (pre-scaled)
constexpr size_t OFF_EPACK = OFF_WPK + 131072;       // [600000] uint2
constexpr size_t WS_WORDS  = OFF_EPACK + 1200000;

// ---------------- one-time prep: pack w_hh (both layers) to fp16 pairs,
// pre-scaled by the gate's exp2 constant.
// wpk index (within layer) = ((dir*128+q)*4 + s)*64 + m*16 + kk
__global__ __launch_bounds__(256) void prep_kernel(
    const float* __restrict__ w_hh0, const float* __restrict__ w_hh1,
    uint32_t* __restrict__ wpk)
{
    int i = blockIdx.x * 256 + threadIdx.x;
    if (i >= 131072) return;
    int layer = i >> 16;
    int r = i & 65535;
    int kk = r & 15, m = (r >> 4) & 3, sidx = (r >> 6) & 3, q = (r >> 8) & 127, dirv = (r >> 15) & 1;
    const float* w = layer ? w_hh1 : w_hh0;
    const float* row = w + ((size_t)dirv * 512 + m * 128 + q) * 128;
    int k0 = 32 * sidx + 2 * kk;
    float sc = (m == 2) ? TANH_SCALE : SIG_SCALE;
    half2_t hv;
    hv.x = (_Float16)(row[k0] * sc);
    hv.y = (_Float16)(row[k0 + 1] * sc);
    wpk[i] = __builtin_bit_cast(uint32_t, hv);
}

// ---------------- layer-0 input projection -> xgT[row][t] (biases folded,
// rows pre-scaled by gate constants)
__global__ __launch_bounds__(512) void xg0_kernel(
    const float* __restrict__ g_mol, const float* __restrict__ w_ih,
    const float* __restrict__ b_ih, const float* __restrict__ b_hh,
    float* __restrict__ xgT)
{
    int b = blockIdx.x;
    int dir = b >> 7, t0 = (b & 127) * 16;
    int r = threadIdx.x;
    __shared__ float xs[272];
    if (r < 272) xs[r] = g_mol[t0 * 17 + r];
    __syncthreads();
    const float* wrow = w_ih + (size_t)(dir * 512 + r) * 17;
    float wv[17];
#pragma unroll
    for (int k = 0; k < 17; ++k) wv[k] = wrow[k];
    float bias = b_ih[dir * 512 + r] + b_hh[dir * 512 + r];
    float rs = ((r >> 7) == 2) ? TANH_SCALE : SIG_SCALE;
    float acc[16];
#pragma unroll
    for (int tt = 0; tt < 16; ++tt) {
        float a = bias;
#pragma unroll
        for (int k = 0; k < 17; ++k) a += xs[tt * 17 + k] * wv[k];
        acc[tt] = a * rs;
    }
    float* orow = xgT + (size_t)(dir * 512 + r) * 2048 + t0;
    *(float4*)(orow + 0)  = make_float4(acc[0], acc[1], acc[2], acc[3]);
    *(float4*)(orow + 4)  = make_float4(acc[4], acc[5], acc[6], acc[7]);
    *(float4*)(orow + 8)  = make_float4(acc[8], acc[9], acc[10], acc[11]);
    *(float4*)(orow + 12) = make_float4(acc[12], acc[13], acc[14], acc[15]);
}

// ---------------- layer-1 input projection: hT0 -> xgT[row][t] (pre-scaled)
__global__ __launch_bounds__(512) void xg1_kernel(
    const float* __restrict__ hT0, const float* __restrict__ w_ih,
    const float* __restrict__ b_ih, const float* __restrict__ b_hh,
    float* __restrict__ xgT)
{
    int b = blockIdx.x;
    int dir = b >> 7, t0 = (b & 127) * 16;
    int tid = threadIdx.x;
    __shared__ float xs[16 * 256];            // [tt][k]
    for (int u = tid; u < 1024; u += 512) {
        int k = u >> 2, j4 = u & 3;
        float4 v = *(const float4*)(hT0 + (size_t)k * 2048 + t0 + 4 * j4);
        xs[(4 * j4 + 0) * 256 + k] = v.x;
        xs[(4 * j4 + 1) * 256 + k] = v.y;
        xs[(4 * j4 + 2) * 256 + k] = v.z;
        xs[(4 * j4 + 3) * 256 + k] = v.w;
    }
    __syncthreads();
    int r = tid;
    float bias = b_ih[dir * 512 + r] + b_hh[dir * 512 + r];
    float rs = ((r >> 7) == 2) ? TANH_SCALE : SIG_SCALE;
    float acc[16];
#pragma unroll
    for (int tt = 0; tt < 16; ++tt) acc[tt] = bias;
    const float4* w4 = reinterpret_cast<const float4*>(w_ih + (size_t)(dir * 512 + r) * 256);
    const float4* xs4 = reinterpret_cast<const float4*>(xs);
    for (int k4 = 0; k4 < 64; ++k4) {
        float4 w = w4[k4];
#pragma unroll
        for (int tt = 0; tt < 16; ++tt) {
            float4 x = xs4[tt * 64 + k4];
            acc[tt] += x.x * w.x + x.y * w.y + x.z * w.z + x.w * w.w;
        }
    }
    float* orow = xgT + (size_t)(dir * 512 + r) * 2048 + t0;
    *(float4*)(orow + 0)  = make_float4(acc[0] * rs, acc[1] * rs, acc[2] * rs, acc[3] * rs);
    *(float4*)(orow + 4)  = make_float4(acc[4] * rs, acc[5] * rs, acc[6] * rs, acc[7] * rs);
    *(float4*)(orow + 8)  = make_float4(acc[8] * rs, acc[9] * rs, acc[10] * rs, acc[11] * rs);
    *(float4*)(orow + 12) = make_float4(acc[12] * rs, acc[13] * rs, acc[14] * rs, acc[15] * rs);
}

// ---------------- fused: blocks 0,1 = LSTM recurrence (one per direction);
// blocks 2..255 = side work (mode 0: edge hist + outw; mode 1: CSR gather).
// 84KB LDS -> exactly 1 block/CU; waves_per_eu(2,2) -> 256-VGPR budget.
__global__ __launch_bounds__(512) __attribute__((amdgpu_waves_per_eu(2, 2)))
void lstm_fused_kernel(
    const float* __restrict__ xgT, const uint32_t* __restrict__ wpk,
    float* __restrict__ hT, int mode,
    const int* __restrict__ esrc, const int* __restrict__ edst,
    const float* __restrict__ ew,
    int* __restrict__ deg, float* __restrict__ outw,
    const int* __restrict__ rowp, const uint2* __restrict__ epack,
    const float* __restrict__ feat_seq,
    const float* __restrict__ Wgc1, const float* __restrict__ bgc1,
    float* __restrict__ gsum)
{
    __shared__ __align__(16) float smem[21504];   // 84 KB: forces 1 block/CU
    const int tid = threadIdx.x;

    if (blockIdx.x >= 2) {
        if (mode == 0) {
            int stride = (gridDim.x - 2) * 512;
            for (int e = (blockIdx.x - 2) * 512 + tid; e < NEDGE; e += stride) {
                atomicAdd(&deg[edst[e]], 1);
                atomicAdd(&outw[esrc[e]], ew[e]);
            }
        } else {
            // CSR gather: agg1 row -> relu(agg1@W+b) -> gsum += outw[n]*h1
            float* wt   = smem;            // 16384 = W_gc1 [k][o]
            float* bg   = smem + 16384;    // 128
            float* aggl = smem + 16512;    // 8 waves x 128
            float* gbuf = smem + 17536;    // 128
            {
                float4* d4 = (float4*)wt;
                const float4* s4 = (const float4*)Wgc1;
                for (int u = tid; u < 4096; u += 512) d4[u] = s4[u];
                if (tid < 128) { bg[tid] = bgc1[tid]; gbuf[tid] = 0.f; }
            }
            __syncthreads();
            int wv = tid >> 6, lane = tid & 63;
            float ga0 = 0.f, ga1 = 0.f;
            int nwaves = (gridDim.x - 2) * 8;
            for (int n = (blockIdx.x - 2) * 8 + wv; n < NNODE; n += nwaves) {
                int st = rowp[n];
                int dg = deg[n];
                float a0 = 0.f, a1 = 0.f;
                for (int i = 0; i < dg; ++i) {
                    uint2 ep = epack[st + i];
                    float w = __uint_as_float(ep.y);
                    float2 f = *(const float2*)(feat_seq + (size_t)ep.x * 128 + 2 * lane);
                    a0 += w * f.x;
                    a1 += w * f.y;
                }
                *(float2*)&aggl[wv * 128 + 2 * lane] = make_float2(a0, a1);
                float h0 = bg[2 * lane], h1v = bg[2 * lane + 1];
                for (int k = 0; k < 128; ++k) {
                    float av_ = aggl[wv * 128 + k];
                    float2 wv2 = *(const float2*)&wt[k * 128 + 2 * lane];
                    h0 += av_ * wv2.x;
                    h1v += av_ * wv2.y;
                }
                float ow = outw[n];
                ga0 += ow * fmaxf(h0, 0.f);
                ga1 += ow * fmaxf(h1v, 0.f);
            }
            atomicAdd(&gbuf[2 * lane], ga0);
            atomicAdd(&gbuf[2 * lane + 1], ga1);
            __syncthreads();
            if (tid < 128) atomicAdd(&gsum[tid], gbuf[tid]);
        }
        return;
    }

    // ------------- LSTM recurrence: quad-split DPP, 1 barrier/step -------------
#if __has_builtin(__builtin_amdgcn_s_setprio)
    __builtin_amdgcn_s_setprio(3);
#endif
    const int dir = blockIdx.x;
    const int q = tid >> 2;     // h index 0..127
    const int s = tid & 3;      // k-chunk / finalized gate

    _Float16* hbuf = reinterpret_cast<_Float16*>(smem);   // [2][128]

    // 64 packed-u32 weights: 4 gates x 16 pairs (k in [32s,32s+32)), pre-scaled
    const uint4* wt4 = reinterpret_cast<const uint4*>(
        wpk + (((size_t)(dir * 128 + q) * 4 + s) * 64));
    uint32_t wr[4][16];
#pragma unroll
    for (int m = 0; m < 4; ++m)
#pragma unroll
        for (int j = 0; j < 4; ++j) {
            uint4 wv = wt4[m * 4 + j];
            wr[m][4 * j + 0] = wv.x; wr[m][4 * j + 1] = wv.y;
            wr[m][4 * j + 2] = wv.z; wr[m][4 * j + 3] = wv.w;
        }

    // activation output map: gate s==2 -> tanh form, else sigmoid form
    const float oscale = (s == 2) ? -2.f : 1.f;
    const float obias  = (s == 2) ? 1.f : 0.f;

    if (tid < 128) reinterpret_cast<uint32_t*>(hbuf)[tid] = 0u;  // both buffers
    float c = 0.f;
    float hq[16];
    __syncthreads();

    const float* xrow = xgT + (size_t)(dir * 512 + (s * 128 + q)) * 2048;
    float* hrow = hT + (size_t)(dir * 128 + q) * 2048;

    const int base0 = dir ? 2032 : 0;
    float4 nA = *(const float4*)(xrow + base0);
    float4 nB = *(const float4*)(xrow + base0 + 4);
    float4 nC = *(const float4*)(xrow + base0 + 8);
    float4 nD = *(const float4*)(xrow + base0 + 12);

    for (int s16 = 0; s16 < 128; ++s16) {
        const int base = dir ? (2032 - s16 * 16) : (s16 * 16);
        float4 A = nA, B4 = nB, C4 = nC, D4 = nD;
        if (s16 < 127) {
            const int nb = dir ? (base - 16) : (base + 16);
            nA = *(const float4*)(xrow + nb);
            nB = *(const float4*)(xrow + nb + 4);
            nC = *(const float4*)(xrow + nb + 8);
            nD = *(const float4*)(xrow + nb + 12);
        }
        float xq[16];
        if (dir) {
            xq[0]=D4.w;  xq[1]=D4.z;  xq[2]=D4.y;  xq[3]=D4.x;
            xq[4]=C4.w;  xq[5]=C4.z;  xq[6]=C4.y;  xq[7]=C4.x;
            xq[8]=B4.w;  xq[9]=B4.z;  xq[10]=B4.y; xq[11]=B4.x;
            xq[12]=A.w;  xq[13]=A.z;  xq[14]=A.y;  xq[15]=A.x;
        } else {
            xq[0]=A.x;   xq[1]=A.y;   xq[2]=A.z;   xq[3]=A.w;
            xq[4]=B4.x;  xq[5]=B4.y;  xq[6]=B4.z;  xq[7]=B4.w;
            xq[8]=C4.x;  xq[9]=C4.y;  xq[10]=C4.z; xq[11]=C4.w;
            xq[12]=D4.x; xq[13]=D4.y; xq[14]=D4.z; xq[15]=D4.w;
        }
#pragma unroll
        for (int i = 0; i < 16; ++i) {
            const int p = i & 1;
            const uint4* h4 = reinterpret_cast<const uint4*>(hbuf + p * 128 + s * 32);
            float a0 = 0.f, a1 = 0.f, a2 = 0.f, a3 = 0.f;
#pragma unroll
            for (int j = 0; j < 4; ++j) {
                uint4 hv = h4[j];
                a0 = dot2h(a0, hv.x, wr[0][4 * j + 0]);
                a0 = dot2h(a0, hv.y, wr[0][4 * j + 1]);
                a0 = dot2h(a0, hv.z, wr[0][4 * j + 2]);
                a0 = dot2h(a0, hv.w, wr[0][4 * j + 3]);
                a1 = dot2h(a1, hv.x, wr[1][4 * j + 0]);
                a1 = dot2h(a1, hv.y, wr[1][4 * j + 1]);
                a1 = dot2h(a1, hv.z, wr[1][4 * j + 2]);
                a1 = dot2h(a1, hv.w, wr[1][4 * j + 3]);
                a2 = dot2h(a2, hv.x, wr[2][4 * j + 0]);
                a2 = dot2h(a2, hv.y, wr[2][4 * j + 1]);
                a2 = dot2h(a2, hv.z, wr[2][4 * j + 2]);
                a2 = dot2h(a2, hv.w, wr[2][4 * j + 3]);
                a3 = dot2h(a3, hv.x, wr[3][4 * j + 0]);
                a3 = dot2h(a3, hv.y, wr[3][4 * j + 1]);
                a3 = dot2h(a3, hv.z, wr[3][4 * j + 2]);
                a3 = dot2h(a3, hv.w, wr[3][4 * j + 3]);
            }
            // quad butterfly reduce (DPP, VALU pipe)
            a0 += qperm<QP_XOR1>(a0); a0 += qperm<QP_XOR2>(a0);
            a1 += qperm<QP_XOR1>(a1); a1 += qperm<QP_XOR2>(a1);
            a2 += qperm<QP_XOR1>(a2); a2 += qperm<QP_XOR2>(a2);
            a3 += qperm<QP_XOR1>(a3); a3 += qperm<QP_XOR2>(a3);
            // pick own gate (s), add pre-scaled xg, exp2-activate
            float g01 = (s & 1) ? a1 : a0;
            float g23 = (s & 1) ? a3 : a2;
            float gp = ((s & 2) ? g23 : g01) + xq[i];
            float e = exp2_fast(gp);
            float r = fast_rcp(1.f + e);
            float av_ = fmaf(r, oscale, obias);     // lane s holds gate s of h_q
            // gather the quad's gates (valid at lane s==0: own=i,b1=f,b2=g,b3=o)
            float b1 = qperm<QP_XOR1>(av_);
            float b2 = qperm<QP_XOR2>(av_);
            float b3 = qperm<QP_XOR3>(av_);
            c = fmaf(b1, c, av_ * b2);              // c' = f*c + i*g  (lane 0)
            float e2 = exp2_fast(TANH_SCALE * c);
            float r2 = fast_rcp(1.f + e2);
            float hv = b3 * fmaf(-2.f, r2, 1.f);    // o * tanh(c')    (lane 0)
            if (s == 0) {
                hbuf[(p ^ 1) * 128 + q] = (_Float16)hv;
                hq[dir ? (15 - i) : i] = hv;
            }
            __syncthreads();
        }
        if (s == 0) {
            *(float4*)(hrow + base + 0)  = make_float4(hq[0], hq[1], hq[2], hq[3]);
            *(float4*)(hrow + base + 4)  = make_float4(hq[4], hq[5], hq[6], hq[7]);
            *(float4*)(hrow + base + 8)  = make_float4(hq[8], hq[9], hq[10], hq[11]);
            *(float4*)(hrow + base + 12) = make_float4(hq[12], hq[13], hq[14], hq[15]);
        }
    }
}

// ---------------- CSR scan: deg -> rowp (exclusive), cursor copy
__global__ __launch_bounds__(1024) void scan_kernel(
    const int* __restrict__ deg, int* __restrict__ rowp, int* __restrict__ cur)
{
    __shared__ int part[1024];
    int t = threadIdx.x;
    int lo = t * 49, hi = min(lo + 49, NNODE);
    int s = 0;
    for (int i = lo; i < hi; ++i) s += deg[i];
    part[t] = s;
    __syncthreads();
    for (int off = 1; off < 1024; off <<= 1) {
        int v = (t >= off) ? part[t - off] : 0;
        __syncthreads();
        part[t] += v;
        __syncthreads();
    }
    int run = t ? part[t - 1] : 0;
    for (int i = lo; i < hi; ++i) {
        rowp[i] = run;
        cur[i] = run;
        run += deg[i];
    }
}

// ---------------- CSR fill: epack[pos] = {src, weight}
__global__ __launch_bounds__(512) void fill_kernel(
    const int* __restrict__ esrc, const int* __restrict__ edst,
    const float* __restrict__ ew, int* __restrict__ cur,
    uint2* __restrict__ epack)
{
    int e = blockIdx.x * 512 + threadIdx.x;
    if (e >= NEDGE) return;
    int d = edst[e];
    int pos = atomicAdd(&cur[d], 1);
    epack[pos] = make_uint2((unsigned)esrc[e], __float_as_uint(ew[e]));
}

// ---------------- q/k/v projection from hT1, 16 timesteps per block
__global__ __launch_bounds__(384) void qkv_kernel(
    const float* __restrict__ hT1,
    const float* __restrict__ Wq, const float* __restrict__ bq,
    const float* __restrict__ Wk, const float* __restrict__ bk,
    const float* __restrict__ Wv, const float* __restrict__ bv,
    float* __restrict__ q, float* __restrict__ k, float* __restrict__ v)
{
    int t0 = blockIdx.x * 16, tid = threadIdx.x;
    __shared__ float xs[16 * 256];
    for (int u = tid; u < 1024; u += 384) {
        int kk = u >> 2, j4 = u & 3;
        float4 vv = *(const float4*)(hT1 + (size_t)kk * 2048 + t0 + 4 * j4);
        xs[(4 * j4 + 0) * 256 + kk] = vv.x;
        xs[(4 * j4 + 1) * 256 + kk] = vv.y;
        xs[(4 * j4 + 2) * 256 + kk] = vv.z;
        xs[(4 * j4 + 3) * 256 + kk] = vv.w;
    }
    __syncthreads();
    int which = tid >> 7, j = tid & 127;
    const float* W = (which == 0) ? Wq : (which == 1) ? Wk : Wv;
    const float* B = (which == 0) ? bq : (which == 1) ? bk : bv;
    float* out = (which == 0) ? q : (which == 1) ? k : v;
    float bias = B[j];
    float acc[16];
#pragma unroll
    for (int tt = 0; tt < 16; ++tt) acc[tt] = bias;
    const float4* w4 = reinterpret_cast<const float4*>(W + (size_t)j * 256);
    const float4* xs4 = reinterpret_cast<const float4*>(xs);
    for (int k4 = 0; k4 < 64; ++k4) {
        float4 w = w4[k4];
#pragma unroll
        for (int tt = 0; tt < 16; ++tt) {
            float4 x = xs4[tt * 64 + k4];
            acc[tt] += x.x * w.x + x.y * w.y + x.z * w.z + x.w * w.w;
        }
    }
#pragma unroll
    for (int tt = 0; tt < 16; ++tt) out[(size_t)(t0 + tt) * 128 + j] = acc[tt];
}

// ---------------- scores = q @ k.T / sqrt(128), straight into d_out+1
__global__ __launch_bounds__(256) void scores_kernel(
    const float* __restrict__ q, const float* __restrict__ kmat, float* __restrict__ attn)
{
    int bi = blockIdx.y, bj = blockIdx.x, tid = threadIdx.x;
    __shared__ float qs[16][132];
    __shared__ float ks[16][132];
    for (int u = tid; u < 2048; u += 256) {
        int rr = u >> 7, cc = u & 127;
        qs[rr][cc] = q[(size_t)(bi * 16 + rr) * 128 + cc];
        ks[rr][cc] = kmat[(size_t)(bj * 16 + rr) * 128 + cc];
    }
    __syncthreads();
    int ty = tid >> 4, tx = tid & 15;
    const float4* qrow = reinterpret_cast<const float4*>(&qs[ty][0]);
    const float4* krow = reinterpret_cast<const float4*>(&ks[tx][0]);
    float acc = 0.f;
#pragma unroll
    for (int c4 = 0; c4 < 32; ++c4) {
        float4 a = qrow[c4], b = krow[c4];
        acc += a.x * b.x + a.y * b.y + a.z * b.z + a.w * b.w;
    }
    attn[(size_t)(bi * 16 + ty) * 2048 + (bj * 16 + tx)] = acc * 0.08838834764831845f;
}

// ---------------- softmax per row, in place; saves row 2047
__global__ __launch_bounds__(256) void softmax_kernel(
    float* __restrict__ attn, float* __restrict__ attnrow)
{
    int i = blockIdx.x, tid = threadIdx.x;
    float* row = attn + (size_t)i * 2048;
    __shared__ float red[256];
    float m = -1e30f;
    for (int j = tid; j < 2048; j += 256) m = fmaxf(m, row[j]);
    red[tid] = m; __syncthreads();
    for (int s = 128; s > 0; s >>= 1) { if (tid < s) red[tid] = fmaxf(red[tid], red[tid + s]); __syncthreads(); }
    m = red[0]; __syncthreads();
    float sum = 0.f;
    for (int j = tid; j < 2048; j += 256) sum += __expf(row[j] - m);
    red[tid] = sum; __syncthreads();
    for (int s = 128; s > 0; s >>= 1) { if (tid < s) red[tid] += red[tid + s]; __syncthreads(); }
    float inv = 1.f / red[0];
    for (int j = tid; j < 2048; j += 256) {
        float w = __expf(row[j] - m) * inv;
        row[j] = w;
        if (i == 2047) attnrow[j] = w;
    }
}

// ---------------- av[j] = sum_t attnrow[t] * v[t][j]
__global__ __launch_bounds__(128) void av_kernel(
    const float* __restrict__ attnrow, const float* __restrict__ v, float* __restrict__ av)
{
    int j = threadIdx.x;
    float acc = 0.f;
#pragma unroll 8
    for (int t = 0; t < 2048; ++t) acc += attnrow[t] * v[(size_t)t * 128 + j];
    av[j] = acc;
}

// ---------------- gmol = av @ Wfc.T + bfc -> feats[256..511]
__global__ __launch_bounds__(256) void gmolfc_kernel(
    const float* __restrict__ av, const float* __restrict__ Wfc, const float* __restrict__ bfc,
    float* __restrict__ feats)
{
    int o = threadIdx.x;
    __shared__ float a[128];
    if (o < 128) a[o] = av[o];
    __syncthreads();
    const float4* w4 = reinterpret_cast<const float4*>(Wfc + (size_t)o * 128);
    const float4* a4 = reinterpret_cast<const float4*>(a);
    float acc = bfc[o];
#pragma unroll 8
    for (int kk = 0; kk < 32; ++kk) {
        float4 w = w4[kk], x = a4[kk];
        acc += x.x * w.x + x.y * w.y + x.z * w.z + x.w * w.w;
    }
    feats[256 + o] = acc;
}

// ---------------- feats: hg (=(gsum/N)@W_gc2+b_gc2) + smiles + kmer
__global__ __launch_bounds__(256) void feats_kernel(
    const float* __restrict__ gsum, const float* __restrict__ W_gc2, const float* __restrict__ b_gc2,
    const float* __restrict__ smiles, const float* __restrict__ kmer, float* __restrict__ feats)
{
    int i = blockIdx.x * 256 + threadIdx.x;
    if (i < 256) {
        float dotv = 0.f;
#pragma unroll 4
        for (int k = 0; k < 128; ++k) dotv += gsum[k] * W_gc2[(size_t)k * 256 + i];
        feats[i] = b_gc2[i] + dotv * (1.f / (float)NNODE);
    } else if (i >= 512 && i < 1086) {
        feats[i] = smiles[i - 512];
    } else if (i >= 1086 && i < 1150) {
        feats[i] = kmer[i - 1086];
    }
}

// ---------------- MLP layers
__global__ __launch_bounds__(256) void mlp1_kernel(
    const float* __restrict__ feats, const float* __restrict__ W1, const float* __restrict__ b1,
    float* __restrict__ f1)
{
    int o = blockIdx.x, tid = threadIdx.x;
    const float* w = W1 + (size_t)o * 1150;
    float acc = 0.f;
    for (int k = tid; k < 1150; k += 256) acc += feats[k] * w[k];
    __shared__ float red[256];
    red[tid] = acc; __syncthreads();
    for (int s = 128; s > 0; s >>= 1) { if (tid < s) red[tid] += red[tid + s]; __syncthreads(); }
    if (tid == 0) f1[o] = fmaxf(red[0] + b1[o], 0.f);
}

__global__ __launch_bounds__(256) void mlp2_kernel(
    const float* __restrict__ f1, const float* __restrict__ W2, const float* __restrict__ b2,
    float* __restrict__ f2)
{
    int o = blockIdx.x, tid = threadIdx.x;
    const float* w = W2 + (size_t)o * 575;
    float acc = 0.f;
    for (int k = tid; k < 575; k += 256) acc += f1[k] * w[k];
    __shared__ float red[256];
    red[tid] = acc; __syncthreads();
    for (int s = 128; s > 0; s >>= 1) { if (tid < s) red[tid] += red[tid + s]; __syncthreads(); }
    if (tid == 0) f2[o] = fmaxf(red[0] + b2[o], 0.f);
}

__global__ __launch_bounds__(256) void mlp_tail_kernel(
    const float* __restrict__ f2,
    const float* __restrict__ W3, const float* __restrict__ b3,
    const float* __restrict__ W4, const float* __restrict__ b4,
    float* __restrict__ out)
{
    __shared__ float f2s[256];
    __shared__ float f3[64];
    int tid = threadIdx.x;
    f2s[tid] = f2[tid];
    __syncthreads();
    if (tid < 64) {
        const float* w = W3 + (size_t)tid * 256;
        float acc = b3[tid];
        for (int k = 0; k < 256; ++k) acc += f2s[k] * w[k];
        f3[tid] = fmaxf(acc, 0.f);
    }
    __syncthreads();
    if (tid == 0) {
        float acc = b4[0];
        for (int k = 0; k < 64; ++k) acc += f3[k] * W4[k];
        out[0] = acc;
    }
}

// ---------------------------------------------------------------------------
extern "C" void kernel_launch(void* const* d_in, const int* in_sizes, int n_in,
                              void* d_out, int out_size, void* d_ws, size_t ws_size,
                              hipStream_t stream)
{
    const float* g_mol   = (const float*)d_in[0];
    const float* feat_seq= (const float*)d_in[1];
    const float* smiles  = (const float*)d_in[2];
    const float* kmer    = (const float*)d_in[3];
    const float* edge_w  = (const float*)d_in[4];
    const float* w_ih0   = (const float*)d_in[5];
    const float* w_hh0   = (const float*)d_in[6];
    const float* b_ih0   = (const float*)d_in[7];
    const float* b_hh0   = (const float*)d_in[8];
    const float* w_ih1   = (const float*)d_in[9];
    const float* w_hh1   = (const float*)d_in[10];
    const float* b_ih1   = (const float*)d_in[11];
    const float* b_hh1   = (const float*)d_in[12];
    const float* Wq      = (const float*)d_in[13];
    const float* bq      = (const float*)d_in[14];
    const float* Wk      = (const float*)d_in[15];
    const float* bk      = (const float*)d_in[16];
    const float* Wv      = (const float*)d_in[17];
    const float* bv      = (const float*)d_in[18];
    const float* Wfc     = (const float*)d_in[19];
    const float* bfc     = (const float*)d_in[20];
    const float* W_gc1   = (const float*)d_in[21];
    const float* b_gc1   = (const float*)d_in[22];
    const float* W_gc2   = (const float*)d_in[23];
    const float* b_gc2   = (const float*)d_in[24];
    const float* W1      = (const float*)d_in[25];
    const float* b1      = (const float*)d_in[26];
    const float* W2      = (const float*)d_in[27];
    const float* b2      = (const float*)d_in[28];
    const float* W3      = (const float*)d_in[29];
    const float* b3      = (const float*)d_in[30];
    const float* W4      = (const float*)d_in[31];
    const float* b4      = (const float*)d_in[32];
    const int* esrc      = (const int*)d_in[33];
    const int* edst      = (const int*)d_in[34];

    float* ws    = (float*)d_ws;
    float* xgT   = ws + OFF_XGT;
    float* hT0   = ws + OFF_HT0;
    float* hT1   = ws + OFF_HT1;
    float* q     = ws + OFF_Q;
    float* k     = ws + OFF_K;
    float* v     = ws + OFF_V;
    float* arow  = ws + OFF_AROW;
    float* av    = ws + OFF_AV;
    float* feats = ws + OFF_FEATS;
    float* f1    = ws + OFF_F1;
    float* f2    = ws + OFF_F2;
    float* gsum  = ws + OFF_GSUM;
    float* outw  = ws + OFF_OUTW;
    int*   deg   = (int*)(ws + OFF_DEG);
    int*   rowp  = (int*)(ws + OFF_ROWP);
    int*   cur   = (int*)(ws + OFF_CUR);
    uint32_t* wpk = (uint32_t*)(ws + OFF_WPK);
    uint2* epack = (uint2*)(ws + OFF_EPACK);

    float* out_f = (float*)d_out;
    float* attn  = out_f + 1;   // [2048][2048] scores then softmax in place

    // zero gsum + outw + deg (contiguous)
    hipMemsetAsync(gsum, 0, (size_t)(128 + 50000 + 50000) * sizeof(float), stream);

    // weight prep + layer-0 input projection
    prep_kernel<<<512, 256, 0, stream>>>(w_hh0, w_hh1, wpk);
    xg0_kernel<<<256, 512, 0, stream>>>(g_mol, w_ih0, b_ih0, b_hh0, xgT);

    // layer-0 recurrence, edge histogram hidden under it (grid=256: 1 block/CU)
    lstm_fused_kernel<<<256, 512, 0, stream>>>(
        xgT, wpk, hT0, 0, esrc, edst, edge_w, deg, outw,
        rowp, epack, feat_seq, W_gc1, b_gc1, gsum);

    // CSR build
    scan_kernel<<<1, 1024, 0, stream>>>(deg, rowp, cur);
    fill_kernel<<<1172, 512, 0, stream>>>(esrc, edst, edge_w, cur, epack);

    // layer-1 input projection, then recurrence with GNN gather hidden under it
    xg1_kernel<<<256, 512, 0, stream>>>(hT0, w_ih1, b_ih1, b_hh1, xgT);
    lstm_fused_kernel<<<256, 512, 0, stream>>>(
        xgT, wpk + 65536, hT1, 1, esrc, edst, edge_w, deg, outw,
        rowp, epack, feat_seq, W_gc1, b_gc1, gsum);

    // attention
    qkv_kernel<<<128, 384, 0, stream>>>(hT1, Wq, bq, Wk, bk, Wv, bv, q, k, v);
    scores_kernel<<<dim3(128, 128), 256, 0, stream>>>(q, k, attn);
    softmax_kernel<<<2048, 256, 0, stream>>>(attn, arow);
    av_kernel<<<1, 128, 0, stream>>>(arow, v, av);
    gmolfc_kernel<<<1, 256, 0, stream>>>(av, Wfc, bfc, feats);
    feats_kernel<<<5, 256, 0, stream>>>(gsum, W_gc2, b_gc2, smiles, kmer, feats);

    // head
    mlp1_kernel<<<575, 256, 0, stream>>>(feats, W1, b1, f1);
    mlp2_kernel<<<256, 256, 0, stream>>>(f1, W2, b2, f2);
    mlp_tail_kernel<<<1, 256, 0, stream>>>(f2, W3, b3, W4, b4, out_f);
}